// Round 12
// baseline (497.989 us; speedup 1.0000x reference)
//
#include <hip/hip_runtime.h>

#define CDIV(a,b) (((a)+(b)-1)/(b))

typedef __bf16 bf16_t;
typedef unsigned char u8;
typedef bf16_t bf16x8 __attribute__((ext_vector_type(8)));
typedef bf16_t bf16x4 __attribute__((ext_vector_type(4)));
typedef float floatx4 __attribute__((ext_vector_type(4)));
typedef float floatx2 __attribute__((ext_vector_type(2)));

// sigma2: storage position p -> original feature index (within 256).
// NOTE: head-major at 64-elem granularity: positions [h*64, h*64+64) are
// exactly the features of head h.  k_conv exploits this (16B = one head).
__device__ __forceinline__ int sigma2(int p) {
    int tile = p >> 7, hh = (p >> 6) & 1, m = (p >> 2) & 15, c = p & 3;
    return tile * 128 + (hh * 4 + c) * 16 + m;
}

// pack 4 fp32 -> 4 OCP e4m3 bytes
__device__ __forceinline__ unsigned pack4_fp8(float a, float b, float c, float d) {
    int v = __builtin_amdgcn_cvt_pk_fp8_f32(a, b, 0, false);   // bytes [1:0]
    v = __builtin_amdgcn_cvt_pk_fp8_f32(c, d, v, true);        // bytes [3:2]
    return (unsigned)v;
}

// ---------------------------------------------------------------------------
// K1: per-original-edge degree count + edge_attr sum (for self-loop fill)
__global__ void k_deg(const int* __restrict__ ei, const float* __restrict__ ea,
                      int* __restrict__ deg, float* __restrict__ lsum, int E) {
    int e = blockIdx.x * 256 + threadIdx.x;
    if (e >= E) return;
    int d = ei[E + e];
    atomicAdd(&deg[d], 1);
    atomicAdd(&lsum[d], ea[e]);
}

// K3: parallel exclusive scan of (deg[i]+1) -> off[0..n], 3 phases.
__global__ void k_scanA(const int* __restrict__ deg, int* __restrict__ part, int n) {
    __shared__ int sh[256];
    int t = threadIdx.x;
    int i = blockIdx.x * 256 + t;
    int v = (i < n) ? deg[i] + 1 : 0;
    sh[t] = v;
    __syncthreads();
    for (int d = 128; d > 0; d >>= 1) { if (t < d) sh[t] += sh[t + d]; __syncthreads(); }
    if (t == 0) part[blockIdx.x] = sh[0];
}
__global__ void k_scanB(int* __restrict__ part, int nb) {
    __shared__ int sh[256];
    int t = threadIdx.x;
    int v = (t < nb) ? part[t] : 0;
    sh[t] = v;
    __syncthreads();
    for (int d = 1; d < 256; d <<= 1) {
        int u = (t >= d) ? sh[t - d] : 0;
        __syncthreads();
        sh[t] += u;
        __syncthreads();
    }
    if (t < nb) part[t] = sh[t] - v;   // exclusive
}
__global__ void k_scanC(const int* __restrict__ deg, const int* __restrict__ part,
                        int* __restrict__ off, float* __restrict__ lsum, int n) {
    __shared__ int sh[256];
    int t = threadIdx.x;
    int i = blockIdx.x * 256 + t;
    int dv = (i < n) ? deg[i] : 0;
    int v = (i < n) ? dv + 1 : 0;
    sh[t] = v;
    __syncthreads();
    for (int d = 1; d < 256; d <<= 1) {
        int u = (t >= d) ? sh[t - d] : 0;
        __syncthreads();
        sh[t] += u;
        __syncthreads();
    }
    int excl = part[blockIdx.x] + sh[t] - v;
    if (i < n) {
        off[i] = excl;
        lsum[i] = lsum[i] / fmaxf((float)dv, 1.0f);   // loop_attr
    }
    if (i == n - 1) off[n] = excl + v;
}

// K4: CSR fill over extended edges (E originals + n self loops), packed int2.
__global__ void k_fill(const int* __restrict__ ei, const float* __restrict__ ea,
                       const float* __restrict__ lattr, const int* __restrict__ off,
                       int* __restrict__ cursor, int2* __restrict__ csr, int E, int n) {
    int e = blockIdx.x * 256 + threadIdx.x;
    int EE = E + n;
    if (e >= EE) return;
    int s, d; float a;
    if (e < E) { s = ei[e]; d = ei[E + e]; a = ea[e]; }
    else       { s = e - E; d = s;         a = lattr[s]; }
    int pos = off[d] + atomicAdd(&cursor[d], 1);
    csr[pos] = make_int2(s, __float_as_int(a));
}

// K5c: combined weight transpose+cast Wl,Wr[K,256] fp32 -> Wt[512,K] bf16.
__global__ void k_wcast2(const float* __restrict__ Wl, const float* __restrict__ Wr,
                         const float* __restrict__ bl, const float* __restrict__ br,
                         bf16_t* __restrict__ Wt, float* __restrict__ bias2,
                         int K, int kshift, int permK,
                         const float* __restrict__ we, const float* __restrict__ att,
                         const float* __restrict__ cb,
                         float* __restrict__ wep, float* __restrict__ attp,
                         float* __restrict__ cbp) {
    int idx = blockIdx.x * 256 + threadIdx.x;
    if (idx < 512) bias2[idx] = (idx < 256) ? bl[idx] : br[idx - 256];
    if (idx < 256) {
        int sg = sigma2(idx);
        wep[idx] = we[sg]; attp[idx] = att[sg]; cbp[idx] = cb[sg];
    }
    if (idx >= 512 * K) return;
    int nn = idx >> kshift, k = idx & (K - 1);
    int ks = permK ? sigma2(k) : k;
    float v = (nn < 256) ? Wl[ks * 256 + nn] : Wr[ks * 256 + (nn - 256)];
    Wt[idx] = (bf16_t)v;
}

// K6a: layer-1 GEMM with fused encoder, all 512 output cols per block.
// Output XL/XR in fp8 e4m3, sigma2 layout (2x 4B stores per row-slot).
__global__ __launch_bounds__(256) void k_gemm1_fused(
        const float* __restrict__ x, const float* __restrict__ encw,
        const float* __restrict__ encb, const bf16_t* __restrict__ Wt,
        const float* __restrict__ bias2, u8* __restrict__ XL,
        u8* __restrict__ XR, int nrows) {
    __shared__ bf16_t As[128 * 32];
    __shared__ bf16_t Bs[128 * 32];
    int tid = threadIdx.x;
    int w = tid >> 6, lane = tid & 63;
    int quad = lane >> 4, m = lane & 15;
    int row0 = blockIdx.x * 128;
    bf16x8 afr[2][2];
    floatx4 acc[2][8];

    for (int ctile = 0; ctile < 4; ++ctile) {
        int n0 = ctile * 128;
#pragma unroll
        for (int rt = 0; rt < 2; ++rt)
#pragma unroll
            for (int ct = 0; ct < 8; ++ct)
                acc[rt][ct] = (floatx4){0.f, 0.f, 0.f, 0.f};
        for (int k0c = 0; k0c < 2; ++k0c) {
            __syncthreads();
            if (ctile == 0) {
#pragma unroll
                for (int i = 0; i < 2; ++i) {  // stage A: fused encoder
                    int c = tid + i * 256;
                    int r = c >> 2, kc = c & 3;
                    int sw = (kc + (r >> 1)) & 3;
                    int gr = row0 + r; if (gr >= nrows) gr = nrows - 1;
                    float4 xv = ((const float4*)x)[gr];
                    bf16x8 v;
#pragma unroll
                    for (int kk = 0; kk < 8; ++kk) {
                        int k = k0c * 32 + kc * 8 + kk;
                        float s = encb[k];
                        s = fmaf(xv.x, encw[k], s);
                        s = fmaf(xv.y, encw[64 + k], s);
                        s = fmaf(xv.z, encw[128 + k], s);
                        s = fmaf(xv.w, encw[192 + k], s);
                        v[kk] = (bf16_t)fmaxf(s, 0.0f);
                    }
                    *(bf16x8*)&As[r * 32 + sw * 8] = v;
                }
            }
#pragma unroll
            for (int i = 0; i < 2; ++i) {      // stage B for this col-tile
                int c = tid + i * 256;
                int r = c >> 2, kc = c & 3;
                int sw = (kc + (r >> 1)) & 3;
                bf16x8 v = *(const bf16x8*)&Wt[(size_t)(n0 + r) * 64 + k0c * 32 + kc * 8];
                *(bf16x8*)&Bs[r * 32 + sw * 8] = v;
            }
            __syncthreads();
            if (ctile == 0) {
#pragma unroll
                for (int rt = 0; rt < 2; ++rt) {
                    int ar = w * 32 + rt * 16 + m;
                    afr[k0c][rt] = *(bf16x8*)&As[ar * 32 + (((quad + (ar >> 1)) & 3) * 8)];
                }
            }
            bf16x8 bfr[8];
#pragma unroll
            for (int ct = 0; ct < 8; ++ct) {
                int br = ct * 16 + m;
                bfr[ct] = *(bf16x8*)&Bs[br * 32 + (((quad + (br >> 1)) & 3) * 8)];
            }
#pragma unroll
            for (int ct = 0; ct < 8; ++ct) {
                acc[0][ct] = __builtin_amdgcn_mfma_f32_16x16x32_bf16(afr[k0c][0], bfr[ct], acc[0][ct], 0, 0, 0);
                acc[1][ct] = __builtin_amdgcn_mfma_f32_16x16x32_bf16(afr[k0c][1], bfr[ct], acc[1][ct], 0, 0, 0);
            }
        }
        int tile = ctile & 1;
        u8* dst = (ctile < 2) ? XL : XR;
        float bv[8];
#pragma unroll
        for (int ct = 0; ct < 8; ++ct) bv[ct] = bias2[n0 + ct * 16 + m];
#pragma unroll
        for (int rt = 0; rt < 2; ++rt) {
#pragma unroll
            for (int i = 0; i < 4; ++i) {
                int row = row0 + w * 32 + rt * 16 + quad * 4 + i;
                if (row < nrows) {
                    unsigned w0 = pack4_fp8(acc[rt][0][i] + bv[0], acc[rt][1][i] + bv[1],
                                            acc[rt][2][i] + bv[2], acc[rt][3][i] + bv[3]);
                    unsigned w1 = pack4_fp8(acc[rt][4][i] + bv[4], acc[rt][5][i] + bv[5],
                                            acc[rt][6][i] + bv[6], acc[rt][7][i] + bv[7]);
                    *(unsigned*)&dst[(size_t)row * 256 + tile * 128 + m * 4] = w0;
                    *(unsigned*)&dst[(size_t)row * 256 + tile * 128 + 64 + m * 4] = w1;
                }
            }
        }
    }
}

// K6b: layer-2 GEMM (K=256), all 512 cols per block; fp8 sigma2 output.
__global__ __launch_bounds__(256) void k_gemm2(
        const bf16_t* __restrict__ Hb, const bf16_t* __restrict__ Wt,
        const float* __restrict__ bias2, u8* __restrict__ XL,
        u8* __restrict__ XR, int nrows) {
    const int K = 256;
    __shared__ bf16_t As[128 * 32];
    __shared__ bf16_t Bs[128 * 32];
    int tid = threadIdx.x;
    int w = tid >> 6, lane = tid & 63;
    int quad = lane >> 4, m = lane & 15;
    int row0 = blockIdx.x * 128;
    bf16x8 afr[8][2];
    floatx4 acc[2][8];

    for (int ctile = 0; ctile < 4; ++ctile) {
        int n0 = ctile * 128;
#pragma unroll
        for (int rt = 0; rt < 2; ++rt)
#pragma unroll
            for (int ct = 0; ct < 8; ++ct)
                acc[rt][ct] = (floatx4){0.f, 0.f, 0.f, 0.f};
        for (int k0c = 0; k0c < 8; ++k0c) {
            __syncthreads();
            if (ctile == 0) {
#pragma unroll
                for (int i = 0; i < 2; ++i) {
                    int c = tid + i * 256;
                    int r = c >> 2, kc = c & 3;
                    int sw = (kc + (r >> 1)) & 3;
                    int gr = row0 + r; if (gr >= nrows) gr = nrows - 1;
                    bf16x8 v = *(const bf16x8*)&Hb[(size_t)gr * K + k0c * 32 + kc * 8];
                    *(bf16x8*)&As[r * 32 + sw * 8] = v;
                }
            }
#pragma unroll
            for (int i = 0; i < 2; ++i) {
                int c = tid + i * 256;
                int r = c >> 2, kc = c & 3;
                int sw = (kc + (r >> 1)) & 3;
                bf16x8 v = *(const bf16x8*)&Wt[(size_t)(n0 + r) * K + k0c * 32 + kc * 8];
                *(bf16x8*)&Bs[r * 32 + sw * 8] = v;
            }
            __syncthreads();
            if (ctile == 0) {
#pragma unroll
                for (int rt = 0; rt < 2; ++rt) {
                    int ar = w * 32 + rt * 16 + m;
                    afr[k0c][rt] = *(bf16x8*)&As[ar * 32 + (((quad + (ar >> 1)) & 3) * 8)];
                }
            }
            bf16x8 bfr[8];
#pragma unroll
            for (int ct = 0; ct < 8; ++ct) {
                int br = ct * 16 + m;
                bfr[ct] = *(bf16x8*)&Bs[br * 32 + (((quad + (br >> 1)) & 3) * 8)];
            }
#pragma unroll
            for (int ct = 0; ct < 8; ++ct) {
                acc[0][ct] = __builtin_amdgcn_mfma_f32_16x16x32_bf16(afr[k0c][0], bfr[ct], acc[0][ct], 0, 0, 0);
                acc[1][ct] = __builtin_amdgcn_mfma_f32_16x16x32_bf16(afr[k0c][1], bfr[ct], acc[1][ct], 0, 0, 0);
            }
        }
        int tile = ctile & 1;
        u8* dst = (ctile < 2) ? XL : XR;
        float bv[8];
#pragma unroll
        for (int ct = 0; ct < 8; ++ct) bv[ct] = bias2[n0 + ct * 16 + m];
#pragma unroll
        for (int rt = 0; rt < 2; ++rt) {
#pragma unroll
            for (int i = 0; i < 4; ++i) {
                int row = row0 + w * 32 + rt * 16 + quad * 4 + i;
                if (row < nrows) {
                    unsigned w0 = pack4_fp8(acc[rt][0][i] + bv[0], acc[rt][1][i] + bv[1],
                                            acc[rt][2][i] + bv[2], acc[rt][3][i] + bv[3]);
                    unsigned w1 = pack4_fp8(acc[rt][4][i] + bv[4], acc[rt][5][i] + bv[5],
                                            acc[rt][6][i] + bv[6], acc[rt][7][i] + bv[7]);
                    *(unsigned*)&dst[(size_t)row * 256 + tile * 128 + m * 4] = w0;
                    *(unsigned*)&dst[(size_t)row * 256 + tile * 128 + 64 + m * 4] = w1;
                }
            }
        }
    }
}

// K7: fused GATv2 conv, fp8 XL/XR, sigma2 layout.  One wave per dst node,
// FOUR 16-lane quarters each on a different edge; lane covers 16 features
// (one uint4 = one 64B head block -> head = l>>2).  Halves gather
// lane-addresses per edge vs the 32-lane scheme (R10 showed conv is
// request-bound: fp8 halved bytes but only -6% time).
// NOTE: no __launch_bounds__ — R7 showed higher occupancy thrashes L2.
// NOTE: pool fusion reverted — R9: concurrent same-graph atomics serialize.
template<bool HI>
__device__ __forceinline__ floatx2 cvtf8(unsigned v) {
    return __builtin_amdgcn_cvt_pk_f32_fp8(v, HI);   // HI is constexpr
}

__device__ __forceinline__ void quad_step(
        int p, int p1, int quarter, int loff,
        const int2* __restrict__ csr, const u8* __restrict__ XL,
        const floatx2* __restrict__ xr, const floatx2* __restrict__ wv,
        const floatx2* __restrict__ av,
        float& s, floatx2* __restrict__ a) {
    int idx = p + quarter;
    bool valid = idx < p1;
    int idc = valid ? idx : p1 - 1;
    int2 ed = csr[idc];
    int src = ed.x;
    float eav = __int_as_float(ed.y);
    uint4 u = *(const uint4*)(XL + (size_t)src * 256 + loff);
    floatx2 x[8];
    x[0] = cvtf8<false>(u.x); x[1] = cvtf8<true>(u.x);
    x[2] = cvtf8<false>(u.y); x[3] = cvtf8<true>(u.y);
    x[4] = cvtf8<false>(u.z); x[5] = cvtf8<true>(u.z);
    x[6] = cvtf8<false>(u.w); x[7] = cvtf8<true>(u.w);
    floatx2 d = {0.f, 0.f};
#pragma unroll
    for (int i = 0; i < 8; ++i) {
        floatx2 t = x[i] + xr[i] + eav * wv[i];
        t = __builtin_elementwise_max(t, 0.2f * t);
        d += t * av[i];
    }
    float al = d.x + d.y;
    al += __shfl_xor(al, 1);
    al += __shfl_xor(al, 2);       // 4-lane head-group reduce
    float wg = valid ? exp2f(al) : 0.0f;   // att pre-scaled by 1/ln2
    s += wg;
#pragma unroll
    for (int i = 0; i < 8; ++i) a[i] += wg * x[i];
}

__global__ void k_conv(
                       const u8* __restrict__ XL, const u8* __restrict__ XR,
                       const float* __restrict__ wep, const float* __restrict__ attp,
                       const int2* __restrict__ csr,
                       const int* __restrict__ off, const float* __restrict__ cbp,
                       bf16_t* __restrict__ outb, int n) {
    int wid = (blockIdx.x * 256 + threadIdx.x) >> 6;
    int lane = threadIdx.x & 63;
    if (wid >= n) return;
    int l = lane & 15, quarter = lane >> 4;
    int loff = l * 16;
    uint4 ur = *(const uint4*)(XR + (size_t)wid * 256 + loff);
    floatx2 xr[8];
    xr[0] = cvtf8<false>(ur.x); xr[1] = cvtf8<true>(ur.x);
    xr[2] = cvtf8<false>(ur.y); xr[3] = cvtf8<true>(ur.y);
    xr[4] = cvtf8<false>(ur.z); xr[5] = cvtf8<true>(ur.z);
    xr[6] = cvtf8<false>(ur.w); xr[7] = cvtf8<true>(ur.w);
    floatx2 wv[8], av[8];
    const float LOG2E = 1.44269504f;
#pragma unroll
    for (int j = 0; j < 4; ++j) {
        float4 wj = ((const float4*)wep)[4 * l + j];
        float4 aj = ((const float4*)attp)[4 * l + j];
        wv[2 * j]     = (floatx2){wj.x, wj.y};
        wv[2 * j + 1] = (floatx2){wj.z, wj.w};
        av[2 * j]     = (floatx2){aj.x * LOG2E, aj.y * LOG2E};
        av[2 * j + 1] = (floatx2){aj.z * LOG2E, aj.w * LOG2E};
    }
    int p0 = off[wid], p1 = off[wid + 1];
    float s = 0.f;
    floatx2 a[8];
#pragma unroll
    for (int i = 0; i < 8; ++i) a[i] = (floatx2){0.f, 0.f};
    int p = p0;
    for (; p + 8 <= p1; p += 8) {
        quad_step(p,     p1, quarter, loff, csr, XL, xr, wv, av, s, a);
        quad_step(p + 4, p1, quarter, loff, csr, XL, xr, wv, av, s, a);
    }
    for (; p < p1; p += 4)
        quad_step(p,     p1, quarter, loff, csr, XL, xr, wv, av, s, a);
    // combine the four quarters (lanes l, l+16, l+32, l+48 hold same features)
    s += __shfl_xor(s, 16);
    s += __shfl_xor(s, 32);
#pragma unroll
    for (int i = 0; i < 8; ++i) {
        a[i].x += __shfl_xor(a[i].x, 16); a[i].y += __shfl_xor(a[i].y, 16);
        a[i].x += __shfl_xor(a[i].x, 32); a[i].y += __shfl_xor(a[i].y, 32);
    }
    if (quarter == 0) {
        float inv = 1.0f / s;
        bf16x8 ob0, ob1;
#pragma unroll
        for (int j = 0; j < 4; ++j) {
            float4 bj = ((const float4*)cbp)[4 * l + j];
            float o0 = fmaxf(fmaf(a[2 * j].x,     inv, bj.x), 0.f);
            float o1 = fmaxf(fmaf(a[2 * j].y,     inv, bj.y), 0.f);
            float o2 = fmaxf(fmaf(a[2 * j + 1].x, inv, bj.z), 0.f);
            float o3 = fmaxf(fmaf(a[2 * j + 1].y, inv, bj.w), 0.f);
            if (j < 2) {
                ob0[j * 4 + 0] = (bf16_t)o0; ob0[j * 4 + 1] = (bf16_t)o1;
                ob0[j * 4 + 2] = (bf16_t)o2; ob0[j * 4 + 3] = (bf16_t)o3;
            } else {
                ob1[(j - 2) * 4 + 0] = (bf16_t)o0; ob1[(j - 2) * 4 + 1] = (bf16_t)o1;
                ob1[(j - 2) * 4 + 2] = (bf16_t)o2; ob1[(j - 2) * 4 + 3] = (bf16_t)o3;
            }
        }
        *(bf16x8*)&outb[(size_t)wid * 256 + l * 16]     = ob0;
        *(bf16x8*)&outb[(size_t)wid * 256 + l * 16 + 8] = ob1;
    }
}

// K9: global mean pool on bf16 input (sigma2 order preserved in gsum).
// 32-node chunks, running accumulator, ~1 flush per graph per column.
__global__ void k_pool(const bf16_t* __restrict__ h, const int* __restrict__ batch,
                       float* __restrict__ gsum, float* __restrict__ gcnt, int n) {
    int j = threadIdx.x;
    int start = blockIdx.x * 32;
    if (start >= n) return;
    int end = start + 32; if (end > n) end = n;
    int cur = batch[start];
    float acc = 0.0f, cnt = 0.0f;
    for (int i = start; i < end; ++i) {
        int g = batch[i];
        if (g != cur) {
            atomicAdd(&gsum[cur * 256 + j], acc);
            if (j == 0) atomicAdd(&gcnt[cur], cnt);
            acc = 0.0f; cnt = 0.0f; cur = g;
        }
        acc += (float)h[(size_t)i * 256 + j];
        cnt += 1.0f;
    }
    atomicAdd(&gsum[cur * 256 + j], acc);
    if (j == 0) atomicAdd(&gcnt[cur], cnt);
}

// K10: post MLP.  gsum is in sigma2 order -> un-permute when loading gv.
__global__ void k_mlp(const float* __restrict__ gsum, const float* __restrict__ gcnt,
                      const float* __restrict__ p1w, const float* __restrict__ p1b,
                      const float* __restrict__ lng, const float* __restrict__ lnb,
                      const float* __restrict__ p2w, const float* __restrict__ p2b,
                      float* __restrict__ out) {
    int g = blockIdx.x;
    int t = threadIdx.x; // 128
    __shared__ float gv[256];
    __shared__ float z[128];
    __shared__ float red[128];
    float invc = 1.0f / fmaxf(gcnt[g], 1.0f);
    gv[sigma2(t)]       = gsum[g * 256 + t] * invc;
    gv[sigma2(t + 128)] = gsum[g * 256 + 128 + t] * invc;
    __syncthreads();
    float z1 = p1b[t];
    for (int k = 0; k < 256; ++k) z1 = fmaf(gv[k], p1w[k * 128 + t], z1);
    red[t] = z1;
    __syncthreads();
    for (int d = 64; d > 0; d >>= 1) { if (t < d) red[t] += red[t + d]; __syncthreads(); }
    float mu = red[0] * (1.0f / 128.0f);
    __syncthreads();
    float dz = z1 - mu;
    red[t] = dz * dz;
    __syncthreads();
    for (int d = 64; d > 0; d >>= 1) { if (t < d) red[t] += red[t + d]; __syncthreads(); }
    float var = red[0] * (1.0f / 128.0f);
    float zn = dz * rsqrtf(var + 1e-5f) * lng[t] + lnb[t];
    z[t] = fmaxf(zn, 0.0f);
    __syncthreads();
    if (t < 64) {
        float o = p2b[t];
        for (int k = 0; k < 128; ++k) o = fmaf(z[k], p2w[k * 64 + t], o);
        out[g * 64 + t] = fmaxf(o, 0.0f);
    }
}

extern "C" void kernel_launch(void* const* d_in, const int* in_sizes, int n_in,
                              void* d_out, int out_size, void* d_ws, size_t ws_size,
                              hipStream_t stream) {
    const float* x      = (const float*)d_in[0];
    const int*   ei     = (const int*)d_in[1];
    const float* ea     = (const float*)d_in[2];
    const int*   batch  = (const int*)d_in[3];
    const float* enc_w  = (const float*)d_in[4];
    const float* enc_b  = (const float*)d_in[5];
    const float* g1_wl  = (const float*)d_in[6];
    const float* g1_bl  = (const float*)d_in[7];
    const float* g1_wr  = (const float*)d_in[8];
    const float* g1_br  = (const float*)d_in[9];
    const float* g1_we  = (const float*)d_in[10];
    const float* g1_att = (const float*)d_in[11];
    const float* g1_bias= (const float*)d_in[12];
    const float* g2_wl  = (const float*)d_in[13];
    const float* g2_bl  = (const float*)d_in[14];
    const float* g2_wr  = (const float*)d_in[15];
    const float* g2_br  = (const float*)d_in[16];
    const float* g2_we  = (const float*)d_in[17];
    const float* g2_att = (const float*)d_in[18];
    const float* g2_bias= (const float*)d_in[19];
    const float* p1_w   = (const float*)d_in[20];
    const float* p1_b   = (const float*)d_in[21];
    const float* ln_g   = (const float*)d_in[22];
    const float* ln_b   = (const float*)d_in[23];
    const float* p2_w   = (const float*)d_in[24];
    const float* p2_b   = (const float*)d_in[25];
    float* out = (float*)d_out;

    const int N  = in_sizes[3];
    const int E  = in_sizes[1] / 2;
    const int EE = E + N;
    const int NB = CDIV(N, 256);

    // workspace carve
    u8*     XL  = (u8*)d_ws;                   // [N,256] fp8 (sigma2)
    u8*     XR  = XL + (size_t)N * 256;        // [N,256] fp8 (sigma2)
    bf16_t* Hb  = (bf16_t*)(XR + (size_t)N * 256); // [N,256] bf16 (conv out)
    bf16_t* Wt  = Hb + (size_t)N * 256;        // [512,256] bf16
    int2*  csr  = (int2*)(Wt + 512 * 256);     // [EE] packed {src, ea}
    float* lsum  = (float*)(csr + EE);         // [N]  -- zeroed region start
    float* gsum  = lsum + N;                   // [32*256]
    float* gcnt  = gsum + 32 * 256;            // [32]
    int*   deg   = (int*)(gcnt + 32);          // [N]
    int*   cursor= deg + N;                    // [N]  -- zeroed region end
    float* bias2 = (float*)(cursor + N);       // [512]
    float* wep   = bias2 + 512;                // [256]
    float* attp  = wep + 256;                  // [256]
    float* cbp   = attp + 256;                 // [256]
    int*   part  = (int*)(cbp + 256);          // [256]
    int*   off   = part + 256;                 // [N+1]

    (void)hipMemsetAsync(lsum, 0, (size_t)(3 * N + 32 * 256 + 32) * sizeof(float), stream);

    k_deg<<<CDIV(E, 256), 256, 0, stream>>>(ei, ea, deg, lsum, E);
    k_scanA<<<NB, 256, 0, stream>>>(deg, part, N);
    k_scanB<<<1, 256, 0, stream>>>(part, NB);
    k_scanC<<<NB, 256, 0, stream>>>(deg, part, off, lsum, N);
    k_fill<<<CDIV(EE, 256), 256, 0, stream>>>(ei, ea, lsum, off, cursor, csr, E, N);

    // ---- GAT layer 1 (encoder fused into GEMM A-staging, K=64) ----
    k_wcast2<<<CDIV(512 * 64, 256), 256, 0, stream>>>(g1_wl, g1_wr, g1_bl, g1_br, Wt, bias2,
                                                      64, 6, 0, g1_we, g1_att, g1_bias,
                                                      wep, attp, cbp);
    k_gemm1_fused<<<CDIV(N, 128), 256, 0, stream>>>(x, enc_w, enc_b, Wt, bias2, XL, XR, N);
    k_conv<<<CDIV(N, 4), 256, 0, stream>>>(XL, XR, wep, attp, csr, off, cbp, Hb, N);

    // ---- GAT layer 2 (K sigma2-permuted to match Hb layout) ----
    k_wcast2<<<CDIV(512 * 256, 256), 256, 0, stream>>>(g2_wl, g2_wr, g2_bl, g2_br, Wt, bias2,
                                                       256, 8, 1, g2_we, g2_att, g2_bias,
                                                       wep, attp, cbp);
    k_gemm2<<<CDIV(N, 128), 256, 0, stream>>>(Hb, Wt, bias2, XL, XR, N);
    k_conv<<<CDIV(N, 4), 256, 0, stream>>>(XL, XR, wep, attp, csr, off, cbp, Hb, N);

    // ---- pool + MLP ----
    k_pool<<<CDIV(N, 32), 256, 0, stream>>>(Hb, batch, gsum, gcnt, N);
    k_mlp<<<32, 128, 0, stream>>>(gsum, gcnt, p1_w, p1_b, ln_g, ln_b, p2_w, p2_b, out);
}

// Round 13
// 465.804 us; speedup vs baseline: 1.0691x; 1.0691x over previous
//
#include <hip/hip_runtime.h>

#define CDIV(a,b) (((a)+(b)-1)/(b))

typedef __bf16 bf16_t;
typedef unsigned char u8;
typedef bf16_t bf16x8 __attribute__((ext_vector_type(8)));
typedef bf16_t bf16x4 __attribute__((ext_vector_type(4)));
typedef float floatx4 __attribute__((ext_vector_type(4)));
typedef float floatx2 __attribute__((ext_vector_type(2)));

// sigma2: storage position p -> original feature index (within 256).
__device__ __forceinline__ int sigma2(int p) {
    int tile = p >> 7, hh = (p >> 6) & 1, m = (p >> 2) & 15, c = p & 3;
    return tile * 128 + (hh * 4 + c) * 16 + m;
}

// pack 4 fp32 -> 4 OCP e4m3 bytes
__device__ __forceinline__ unsigned pack4_fp8(float a, float b, float c, float d) {
    int v = __builtin_amdgcn_cvt_pk_fp8_f32(a, b, 0, false);   // bytes [1:0]
    v = __builtin_amdgcn_cvt_pk_fp8_f32(c, d, v, true);        // bytes [3:2]
    return (unsigned)v;
}

template<bool HI>
__device__ __forceinline__ floatx2 cvtf8(unsigned v) {
    return __builtin_amdgcn_cvt_pk_f32_fp8(v, HI);   // HI is constexpr
}

// ---------------------------------------------------------------------------
// K1: per-original-edge degree count + edge_attr sum (for self-loop fill)
__global__ void k_deg(const int* __restrict__ ei, const float* __restrict__ ea,
                      int* __restrict__ deg, float* __restrict__ lsum, int E) {
    int e = blockIdx.x * 256 + threadIdx.x;
    if (e >= E) return;
    int d = ei[E + e];
    atomicAdd(&deg[d], 1);
    atomicAdd(&lsum[d], ea[e]);
}

// K3: parallel exclusive scan of (deg[i]+1) -> off[0..n], 3 phases.
__global__ void k_scanA(const int* __restrict__ deg, int* __restrict__ part, int n) {
    __shared__ int sh[256];
    int t = threadIdx.x;
    int i = blockIdx.x * 256 + t;
    int v = (i < n) ? deg[i] + 1 : 0;
    sh[t] = v;
    __syncthreads();
    for (int d = 128; d > 0; d >>= 1) { if (t < d) sh[t] += sh[t + d]; __syncthreads(); }
    if (t == 0) part[blockIdx.x] = sh[0];
}
__global__ void k_scanB(int* __restrict__ part, int nb) {
    __shared__ int sh[256];
    int t = threadIdx.x;
    int v = (t < nb) ? part[t] : 0;
    sh[t] = v;
    __syncthreads();
    for (int d = 1; d < 256; d <<= 1) {
        int u = (t >= d) ? sh[t - d] : 0;
        __syncthreads();
        sh[t] += u;
        __syncthreads();
    }
    if (t < nb) part[t] = sh[t] - v;   // exclusive
}
__global__ void k_scanC(const int* __restrict__ deg, const int* __restrict__ part,
                        int* __restrict__ off, float* __restrict__ lsum, int n) {
    __shared__ int sh[256];
    int t = threadIdx.x;
    int i = blockIdx.x * 256 + t;
    int dv = (i < n) ? deg[i] : 0;
    int v = (i < n) ? dv + 1 : 0;
    sh[t] = v;
    __syncthreads();
    for (int d = 1; d < 256; d <<= 1) {
        int u = (t >= d) ? sh[t - d] : 0;
        __syncthreads();
        sh[t] += u;
        __syncthreads();
    }
    int excl = part[blockIdx.x] + sh[t] - v;
    if (i < n) {
        off[i] = excl;
        lsum[i] = lsum[i] / fmaxf((float)dv, 1.0f);   // loop_attr
    }
    if (i == n - 1) off[n] = excl + v;
}

// K4: CSR fill over extended edges (E originals + n self loops), packed int2.
__global__ void k_fill(const int* __restrict__ ei, const float* __restrict__ ea,
                       const float* __restrict__ lattr, const int* __restrict__ off,
                       int* __restrict__ cursor, int2* __restrict__ csr, int E, int n) {
    int e = blockIdx.x * 256 + threadIdx.x;
    int EE = E + n;
    if (e >= EE) return;
    int s, d; float a;
    if (e < E) { s = ei[e]; d = ei[E + e]; a = ea[e]; }
    else       { s = e - E; d = s;         a = lattr[s]; }
    int pos = off[d] + atomicAdd(&cursor[d], 1);
    csr[pos] = make_int2(s, __float_as_int(a));
}

// K5c: combined weight transpose+cast Wl,Wr[K,256] fp32 -> Wt[512,K] bf16.
__global__ void k_wcast2(const float* __restrict__ Wl, const float* __restrict__ Wr,
                         const float* __restrict__ bl, const float* __restrict__ br,
                         bf16_t* __restrict__ Wt, float* __restrict__ bias2,
                         int K, int kshift, int permK,
                         const float* __restrict__ we, const float* __restrict__ att,
                         const float* __restrict__ cb,
                         float* __restrict__ wep, float* __restrict__ attp,
                         float* __restrict__ cbp) {
    int idx = blockIdx.x * 256 + threadIdx.x;
    if (idx < 512) bias2[idx] = (idx < 256) ? bl[idx] : br[idx - 256];
    if (idx < 256) {
        int sg = sigma2(idx);
        wep[idx] = we[sg]; attp[idx] = att[sg]; cbp[idx] = cb[sg];
    }
    if (idx >= 512 * K) return;
    int nn = idx >> kshift, k = idx & (K - 1);
    int ks = permK ? sigma2(k) : k;
    float v = (nn < 256) ? Wl[ks * 256 + nn] : Wr[ks * 256 + (nn - 256)];
    Wt[idx] = (bf16_t)v;
}

// K6a: layer-1 GEMM with fused encoder.  grid.y=2 splits the 4 col-tiles
// (y=0: XL ctiles 0,1; y=1: XR ctiles 2,3) -> 782 blocks (3.05/CU) for
// load balance; A (fused encoder) computed once per block, fragments cached.
__global__ __launch_bounds__(256) void k_gemm1_fused(
        const float* __restrict__ x, const float* __restrict__ encw,
        const float* __restrict__ encb, const bf16_t* __restrict__ Wt,
        const float* __restrict__ bias2, u8* __restrict__ XL,
        u8* __restrict__ XR, int nrows) {
    __shared__ bf16_t As[128 * 32];
    __shared__ bf16_t Bs[128 * 32];
    int tid = threadIdx.x;
    int w = tid >> 6, lane = tid & 63;
    int quad = lane >> 4, m = lane & 15;
    int row0 = blockIdx.x * 128;
    int ct0 = blockIdx.y * 2;
    bf16x8 afr[2][2];
    floatx4 acc[2][8];

    for (int ctile = ct0; ctile < ct0 + 2; ++ctile) {
        int n0 = ctile * 128;
#pragma unroll
        for (int rt = 0; rt < 2; ++rt)
#pragma unroll
            for (int ct = 0; ct < 8; ++ct)
                acc[rt][ct] = (floatx4){0.f, 0.f, 0.f, 0.f};
        for (int k0c = 0; k0c < 2; ++k0c) {
            __syncthreads();
            if (ctile == ct0) {
#pragma unroll
                for (int i = 0; i < 2; ++i) {  // stage A: fused encoder
                    int c = tid + i * 256;
                    int r = c >> 2, kc = c & 3;
                    int sw = (kc + (r >> 1)) & 3;
                    int gr = row0 + r; if (gr >= nrows) gr = nrows - 1;
                    float4 xv = ((const float4*)x)[gr];
                    bf16x8 v;
#pragma unroll
                    for (int kk = 0; kk < 8; ++kk) {
                        int k = k0c * 32 + kc * 8 + kk;
                        float s = encb[k];
                        s = fmaf(xv.x, encw[k], s);
                        s = fmaf(xv.y, encw[64 + k], s);
                        s = fmaf(xv.z, encw[128 + k], s);
                        s = fmaf(xv.w, encw[192 + k], s);
                        v[kk] = (bf16_t)fmaxf(s, 0.0f);
                    }
                    *(bf16x8*)&As[r * 32 + sw * 8] = v;
                }
            }
#pragma unroll
            for (int i = 0; i < 2; ++i) {      // stage B for this col-tile
                int c = tid + i * 256;
                int r = c >> 2, kc = c & 3;
                int sw = (kc + (r >> 1)) & 3;
                bf16x8 v = *(const bf16x8*)&Wt[(size_t)(n0 + r) * 64 + k0c * 32 + kc * 8];
                *(bf16x8*)&Bs[r * 32 + sw * 8] = v;
            }
            __syncthreads();
            if (ctile == ct0) {
#pragma unroll
                for (int rt = 0; rt < 2; ++rt) {
                    int ar = w * 32 + rt * 16 + m;
                    afr[k0c][rt] = *(bf16x8*)&As[ar * 32 + (((quad + (ar >> 1)) & 3) * 8)];
                }
            }
            bf16x8 bfr[8];
#pragma unroll
            for (int ct = 0; ct < 8; ++ct) {
                int br = ct * 16 + m;
                bfr[ct] = *(bf16x8*)&Bs[br * 32 + (((quad + (br >> 1)) & 3) * 8)];
            }
#pragma unroll
            for (int ct = 0; ct < 8; ++ct) {
                acc[0][ct] = __builtin_amdgcn_mfma_f32_16x16x32_bf16(afr[k0c][0], bfr[ct], acc[0][ct], 0, 0, 0);
                acc[1][ct] = __builtin_amdgcn_mfma_f32_16x16x32_bf16(afr[k0c][1], bfr[ct], acc[1][ct], 0, 0, 0);
            }
        }
        int tile = ctile & 1;
        u8* dst = (ctile < 2) ? XL : XR;
        float bv[8];
#pragma unroll
        for (int ct = 0; ct < 8; ++ct) bv[ct] = bias2[n0 + ct * 16 + m];
#pragma unroll
        for (int rt = 0; rt < 2; ++rt) {
#pragma unroll
            for (int i = 0; i < 4; ++i) {
                int row = row0 + w * 32 + rt * 16 + quad * 4 + i;
                if (row < nrows) {
                    unsigned w0 = pack4_fp8(acc[rt][0][i] + bv[0], acc[rt][1][i] + bv[1],
                                            acc[rt][2][i] + bv[2], acc[rt][3][i] + bv[3]);
                    unsigned w1 = pack4_fp8(acc[rt][4][i] + bv[4], acc[rt][5][i] + bv[5],
                                            acc[rt][6][i] + bv[6], acc[rt][7][i] + bv[7]);
                    *(unsigned*)&dst[(size_t)row * 256 + tile * 128 + m * 4] = w0;
                    *(unsigned*)&dst[(size_t)row * 256 + tile * 128 + 64 + m * 4] = w1;
                }
            }
        }
    }
}

// K6b: layer-2 GEMM (K=256), grid.y=2 col-tile split (same scheme as K6a);
// A staged to LDS once per block, fragments kept in registers for tile 2.
__global__ __launch_bounds__(256) void k_gemm2(
        const bf16_t* __restrict__ Hb, const bf16_t* __restrict__ Wt,
        const float* __restrict__ bias2, u8* __restrict__ XL,
        u8* __restrict__ XR, int nrows) {
    const int K = 256;
    __shared__ bf16_t As[128 * 32];
    __shared__ bf16_t Bs[128 * 32];
    int tid = threadIdx.x;
    int w = tid >> 6, lane = tid & 63;
    int quad = lane >> 4, m = lane & 15;
    int row0 = blockIdx.x * 128;
    int ct0 = blockIdx.y * 2;
    bf16x8 afr[8][2];
    floatx4 acc[2][8];

    for (int ctile = ct0; ctile < ct0 + 2; ++ctile) {
        int n0 = ctile * 128;
#pragma unroll
        for (int rt = 0; rt < 2; ++rt)
#pragma unroll
            for (int ct = 0; ct < 8; ++ct)
                acc[rt][ct] = (floatx4){0.f, 0.f, 0.f, 0.f};
        for (int k0c = 0; k0c < 8; ++k0c) {
            __syncthreads();
            if (ctile == ct0) {
#pragma unroll
                for (int i = 0; i < 2; ++i) {
                    int c = tid + i * 256;
                    int r = c >> 2, kc = c & 3;
                    int sw = (kc + (r >> 1)) & 3;
                    int gr = row0 + r; if (gr >= nrows) gr = nrows - 1;
                    bf16x8 v = *(const bf16x8*)&Hb[(size_t)gr * K + k0c * 32 + kc * 8];
                    *(bf16x8*)&As[r * 32 + sw * 8] = v;
                }
            }
#pragma unroll
            for (int i = 0; i < 2; ++i) {
                int c = tid + i * 256;
                int r = c >> 2, kc = c & 3;
                int sw = (kc + (r >> 1)) & 3;
                bf16x8 v = *(const bf16x8*)&Wt[(size_t)(n0 + r) * K + k0c * 32 + kc * 8];
                *(bf16x8*)&Bs[r * 32 + sw * 8] = v;
            }
            __syncthreads();
            if (ctile == ct0) {
#pragma unroll
                for (int rt = 0; rt < 2; ++rt) {
                    int ar = w * 32 + rt * 16 + m;
                    afr[k0c][rt] = *(bf16x8*)&As[ar * 32 + (((quad + (ar >> 1)) & 3) * 8)];
                }
            }
            bf16x8 bfr[8];
#pragma unroll
            for (int ct = 0; ct < 8; ++ct) {
                int br = ct * 16 + m;
                bfr[ct] = *(bf16x8*)&Bs[br * 32 + (((quad + (br >> 1)) & 3) * 8)];
            }
#pragma unroll
            for (int ct = 0; ct < 8; ++ct) {
                acc[0][ct] = __builtin_amdgcn_mfma_f32_16x16x32_bf16(afr[k0c][0], bfr[ct], acc[0][ct], 0, 0, 0);
                acc[1][ct] = __builtin_amdgcn_mfma_f32_16x16x32_bf16(afr[k0c][1], bfr[ct], acc[1][ct], 0, 0, 0);
            }
        }
        int tile = ctile & 1;
        u8* dst = (ctile < 2) ? XL : XR;
        float bv[8];
#pragma unroll
        for (int ct = 0; ct < 8; ++ct) bv[ct] = bias2[n0 + ct * 16 + m];
#pragma unroll
        for (int rt = 0; rt < 2; ++rt) {
#pragma unroll
            for (int i = 0; i < 4; ++i) {
                int row = row0 + w * 32 + rt * 16 + quad * 4 + i;
                if (row < nrows) {
                    unsigned w0 = pack4_fp8(acc[rt][0][i] + bv[0], acc[rt][1][i] + bv[1],
                                            acc[rt][2][i] + bv[2], acc[rt][3][i] + bv[3]);
                    unsigned w1 = pack4_fp8(acc[rt][4][i] + bv[4], acc[rt][5][i] + bv[5],
                                            acc[rt][6][i] + bv[6], acc[rt][7][i] + bv[7]);
                    *(unsigned*)&dst[(size_t)row * 256 + tile * 128 + m * 4] = w0;
                    *(unsigned*)&dst[(size_t)row * 256 + tile * 128 + 64 + m * 4] = w1;
                }
            }
        }
    }
}

// K7: fused GATv2 conv, fp8 XL/XR (256B/edge), sigma2 layout.  One wave per
// dst node, two 32-lane halves on different edges; lane covers 8 features
// (one head).  R10's empirically-best config: R12's 16-lane/16B variant
// regressed (99us, VALU 49%) — conv is latency-hiding-bound, not
// request-bound; keep short per-lane chains + 48 VGPR.
// NOTE: no __launch_bounds__ — R7 showed higher occupancy thrashes L2.
// NOTE: pool fusion reverted — R9: concurrent same-graph atomics serialize.
__device__ __forceinline__ void pair_step(
        int p, int p1, int half, int loff,
        const int2* __restrict__ csr, const u8* __restrict__ XL,
        floatx2 xr01, floatx2 xr23, floatx2 xr45, floatx2 xr67,
        floatx2 wv01, floatx2 wv23, floatx2 wv45, floatx2 wv67,
        floatx2 av01, floatx2 av23, floatx2 av45, floatx2 av67,
        float& s, floatx2& a01, floatx2& a23, floatx2& a45, floatx2& a67) {
    int idx = p + half;
    bool valid = idx < p1;
    int idc = valid ? idx : p1 - 1;
    int2 ed = csr[idc];
    int src = ed.x;
    float eav = __int_as_float(ed.y);
    uint2 u = *(const uint2*)(XL + (size_t)src * 256 + loff);
    floatx2 x01 = cvtf8<false>(u.x);
    floatx2 x23 = cvtf8<true>(u.x);
    floatx2 x45 = cvtf8<false>(u.y);
    floatx2 x67 = cvtf8<true>(u.y);
    floatx2 t01 = x01 + xr01 + eav * wv01;
    floatx2 t23 = x23 + xr23 + eav * wv23;
    floatx2 t45 = x45 + xr45 + eav * wv45;
    floatx2 t67 = x67 + xr67 + eav * wv67;
    t01 = __builtin_elementwise_max(t01, 0.2f * t01);
    t23 = __builtin_elementwise_max(t23, 0.2f * t23);
    t45 = __builtin_elementwise_max(t45, 0.2f * t45);
    t67 = __builtin_elementwise_max(t67, 0.2f * t67);
    floatx2 d = t01 * av01 + t23 * av23 + t45 * av45 + t67 * av67;
    float al = d.x + d.y;
    al += __shfl_xor(al, 1);
    al += __shfl_xor(al, 2);
    al += __shfl_xor(al, 4);       // 8-lane head group reduce
    float wg = valid ? exp2f(al) : 0.0f;   // att pre-scaled by 1/ln2
    s += wg;
    a01 += wg * x01; a23 += wg * x23; a45 += wg * x45; a67 += wg * x67;
}

__global__ void k_conv(
                       const u8* __restrict__ XL, const u8* __restrict__ XR,
                       const float* __restrict__ wep, const float* __restrict__ attp,
                       const int2* __restrict__ csr,
                       const int* __restrict__ off, const float* __restrict__ cbp,
                       bf16_t* __restrict__ outb, int n) {
    int wid = (blockIdx.x * 256 + threadIdx.x) >> 6;
    int lane = threadIdx.x & 63;
    if (wid >= n) return;
    int l = lane & 31, half = lane >> 5;
    int loff = l * 8;
    uint2 ur = *(const uint2*)(XR + (size_t)wid * 256 + loff);
    floatx2 xr01 = cvtf8<false>(ur.x);
    floatx2 xr23 = cvtf8<true>(ur.x);
    floatx2 xr45 = cvtf8<false>(ur.y);
    floatx2 xr67 = cvtf8<true>(ur.y);
    float4 wa = ((const float4*)wep)[2 * l], wb = ((const float4*)wep)[2 * l + 1];
    float4 aa = ((const float4*)attp)[2 * l], ab = ((const float4*)attp)[2 * l + 1];
    floatx2 wv01 = {wa.x, wa.y}, wv23 = {wa.z, wa.w};
    floatx2 wv45 = {wb.x, wb.y}, wv67 = {wb.z, wb.w};
    const float LOG2E = 1.44269504f;
    floatx2 av01 = {aa.x * LOG2E, aa.y * LOG2E}, av23 = {aa.z * LOG2E, aa.w * LOG2E};
    floatx2 av45 = {ab.x * LOG2E, ab.y * LOG2E}, av67 = {ab.z * LOG2E, ab.w * LOG2E};
    int p0 = off[wid], p1 = off[wid + 1];
    float s = 0.f;
    floatx2 a01 = {0.f, 0.f}, a23 = {0.f, 0.f}, a45 = {0.f, 0.f}, a67 = {0.f, 0.f};
    int p = p0;
    for (; p + 4 <= p1; p += 4) {
        pair_step(p,     p1, half, loff, csr, XL, xr01, xr23, xr45, xr67,
                  wv01, wv23, wv45, wv67, av01, av23, av45, av67, s, a01, a23, a45, a67);
        pair_step(p + 2, p1, half, loff, csr, XL, xr01, xr23, xr45, xr67,
                  wv01, wv23, wv45, wv67, av01, av23, av45, av67, s, a01, a23, a45, a67);
    }
    for (; p < p1; p += 2)
        pair_step(p,     p1, half, loff, csr, XL, xr01, xr23, xr45, xr67,
                  wv01, wv23, wv45, wv67, av01, av23, av45, av67, s, a01, a23, a45, a67);
    // combine the two halves
    s += __shfl_xor(s, 32);
    a01.x += __shfl_xor(a01.x, 32); a01.y += __shfl_xor(a01.y, 32);
    a23.x += __shfl_xor(a23.x, 32); a23.y += __shfl_xor(a23.y, 32);
    a45.x += __shfl_xor(a45.x, 32); a45.y += __shfl_xor(a45.y, 32);
    a67.x += __shfl_xor(a67.x, 32); a67.y += __shfl_xor(a67.y, 32);
    if (half == 0) {
        float inv = 1.0f / s;
        float4 ba = ((const float4*)cbp)[2 * l], bb = ((const float4*)cbp)[2 * l + 1];
        bf16x8 ob;
        ob[0] = (bf16_t)fmaxf(fmaf(a01.x, inv, ba.x), 0.f);
        ob[1] = (bf16_t)fmaxf(fmaf(a01.y, inv, ba.y), 0.f);
        ob[2] = (bf16_t)fmaxf(fmaf(a23.x, inv, ba.z), 0.f);
        ob[3] = (bf16_t)fmaxf(fmaf(a23.y, inv, ba.w), 0.f);
        ob[4] = (bf16_t)fmaxf(fmaf(a45.x, inv, bb.x), 0.f);
        ob[5] = (bf16_t)fmaxf(fmaf(a45.y, inv, bb.y), 0.f);
        ob[6] = (bf16_t)fmaxf(fmaf(a67.x, inv, bb.z), 0.f);
        ob[7] = (bf16_t)fmaxf(fmaf(a67.y, inv, bb.w), 0.f);
        *(bf16x8*)&outb[(size_t)wid * 256 + l * 8] = ob;
    }
}

// K9: global mean pool on bf16 input (sigma2 order preserved in gsum).
__global__ void k_pool(const bf16_t* __restrict__ h, const int* __restrict__ batch,
                       float* __restrict__ gsum, float* __restrict__ gcnt, int n) {
    int j = threadIdx.x;
    int start = blockIdx.x * 32;
    if (start >= n) return;
    int end = start + 32; if (end > n) end = n;
    int cur = batch[start];
    float acc = 0.0f, cnt = 0.0f;
    for (int i = start; i < end; ++i) {
        int g = batch[i];
        if (g != cur) {
            atomicAdd(&gsum[cur * 256 + j], acc);
            if (j == 0) atomicAdd(&gcnt[cur], cnt);
            acc = 0.0f; cnt = 0.0f; cur = g;
        }
        acc += (float)h[(size_t)i * 256 + j];
        cnt += 1.0f;
    }
    atomicAdd(&gsum[cur * 256 + j], acc);
    if (j == 0) atomicAdd(&gcnt[cur], cnt);
}

// K10: post MLP.  gsum is in sigma2 order -> un-permute when loading gv.
__global__ void k_mlp(const float* __restrict__ gsum, const float* __restrict__ gcnt,
                      const float* __restrict__ p1w, const float* __restrict__ p1b,
                      const float* __restrict__ lng, const float* __restrict__ lnb,
                      const float* __restrict__ p2w, const float* __restrict__ p2b,
                      float* __restrict__ out) {
    int g = blockIdx.x;
    int t = threadIdx.x; // 128
    __shared__ float gv[256];
    __shared__ float z[128];
    __shared__ float red[128];
    float invc = 1.0f / fmaxf(gcnt[g], 1.0f);
    gv[sigma2(t)]       = gsum[g * 256 + t] * invc;
    gv[sigma2(t + 128)] = gsum[g * 256 + 128 + t] * invc;
    __syncthreads();
    float z1 = p1b[t];
    for (int k = 0; k < 256; ++k) z1 = fmaf(gv[k], p1w[k * 128 + t], z1);
    red[t] = z1;
    __syncthreads();
    for (int d = 64; d > 0; d >>= 1) { if (t < d) red[t] += red[t + d]; __syncthreads(); }
    float mu = red[0] * (1.0f / 128.0f);
    __syncthreads();
    float dz = z1 - mu;
    red[t] = dz * dz;
    __syncthreads();
    for (int d = 64; d > 0; d >>= 1) { if (t < d) red[t] += red[t + d]; __syncthreads(); }
    float var = red[0] * (1.0f / 128.0f);
    float zn = dz * rsqrtf(var + 1e-5f) * lng[t] + lnb[t];
    z[t] = fmaxf(zn, 0.0f);
    __syncthreads();
    if (t < 64) {
        float o = p2b[t];
        for (int k = 0; k < 128; ++k) o = fmaf(z[k], p2w[k * 64 + t], o);
        out[g * 64 + t] = fmaxf(o, 0.0f);
    }
}

extern "C" void kernel_launch(void* const* d_in, const int* in_sizes, int n_in,
                              void* d_out, int out_size, void* d_ws, size_t ws_size,
                              hipStream_t stream) {
    const float* x      = (const float*)d_in[0];
    const int*   ei     = (const int*)d_in[1];
    const float* ea     = (const float*)d_in[2];
    const int*   batch  = (const int*)d_in[3];
    const float* enc_w  = (const float*)d_in[4];
    const float* enc_b  = (const float*)d_in[5];
    const float* g1_wl  = (const float*)d_in[6];
    const float* g1_bl  = (const float*)d_in[7];
    const float* g1_wr  = (const float*)d_in[8];
    const float* g1_br  = (const float*)d_in[9];
    const float* g1_we  = (const float*)d_in[10];
    const float* g1_att = (const float*)d_in[11];
    const float* g1_bias= (const float*)d_in[12];
    const float* g2_wl  = (const float*)d_in[13];
    const float* g2_bl  = (const float*)d_in[14];
    const float* g2_wr  = (const float*)d_in[15];
    const float* g2_br  = (const float*)d_in[16];
    const float* g2_we  = (const float*)d_in[17];
    const float* g2_att = (const float*)d_in[18];
    const float* g2_bias= (const float*)d_in[19];
    const float* p1_w   = (const float*)d_in[20];
    const float* p1_b   = (const float*)d_in[21];
    const float* ln_g   = (const float*)d_in[22];
    const float* ln_b   = (const float*)d_in[23];
    const float* p2_w   = (const float*)d_in[24];
    const float* p2_b   = (const float*)d_in[25];
    float* out = (float*)d_out;

    const int N  = in_sizes[3];
    const int E  = in_sizes[1] / 2;
    const int EE = E + N;
    const int NB = CDIV(N, 256);

    // workspace carve
    u8*     XL  = (u8*)d_ws;                   // [N,256] fp8 (sigma2)
    u8*     XR  = XL + (size_t)N * 256;        // [N,256] fp8 (sigma2)
    bf16_t* Hb  = (bf16_t*)(XR + (size_t)N * 256); // [N,256] bf16 (conv out)
    bf16_t* Wt  = Hb + (size_t)N * 256;        // [512,256] bf16
    int2*  csr  = (int2*)(Wt + 512 * 256);     // [EE] packed {src, ea}
    float* lsum  = (float*)(csr + EE);         // [N]  -- zeroed region start
    float* gsum  = lsum + N;                   // [32*256]
    float* gcnt  = gsum + 32 * 256;            // [32]
    int*   deg   = (int*)(gcnt + 32);          // [N]
    int*   cursor= deg + N;                    // [N]  -- zeroed region end
    float* bias2 = (float*)(cursor + N);       // [512]
    float* wep   = bias2 + 512;                // [256]
    float* attp  = wep + 256;                  // [256]
    float* cbp   = attp + 256;                 // [256]
    int*   part  = (int*)(cbp + 256);          // [256]
    int*   off   = part + 256;                 // [N+1]

    (void)hipMemsetAsync(lsum, 0, (size_t)(3 * N + 32 * 256 + 32) * sizeof(float), stream);

    k_deg<<<CDIV(E, 256), 256, 0, stream>>>(ei, ea, deg, lsum, E);
    k_scanA<<<NB, 256, 0, stream>>>(deg, part, N);
    k_scanB<<<1, 256, 0, stream>>>(part, NB);
    k_scanC<<<NB, 256, 0, stream>>>(deg, part, off, lsum, N);
    k_fill<<<CDIV(EE, 256), 256, 0, stream>>>(ei, ea, lsum, off, cursor, csr, E, N);

    dim3 ggrid(CDIV(N, 128), 2);

    // ---- GAT layer 1 (encoder fused into GEMM A-staging, K=64) ----
    k_wcast2<<<CDIV(512 * 64, 256), 256, 0, stream>>>(g1_wl, g1_wr, g1_bl, g1_br, Wt, bias2,
                                                      64, 6, 0, g1_we, g1_att, g1_bias,
                                                      wep, attp, cbp);
    k_gemm1_fused<<<ggrid, 256, 0, stream>>>(x, enc_w, enc_b, Wt, bias2, XL, XR, N);
    k_conv<<<CDIV(N, 4), 256, 0, stream>>>(XL, XR, wep, attp, csr, off, cbp, Hb, N);

    // ---- GAT layer 2 (K sigma2-permuted to match Hb layout) ----
    k_wcast2<<<CDIV(512 * 256, 256), 256, 0, stream>>>(g2_wl, g2_wr, g2_bl, g2_br, Wt, bias2,
                                                       256, 8, 1, g2_we, g2_att, g2_bias,
                                                       wep, attp, cbp);
    k_gemm2<<<ggrid, 256, 0, stream>>>(Hb, Wt, bias2, XL, XR, N);
    k_conv<<<CDIV(N, 4), 256, 0, stream>>>(XL, XR, wep, attp, csr, off, cbp, Hb, N);

    // ---- pool + MLP ----
    k_pool<<<CDIV(N, 32), 256, 0, stream>>>(Hb, batch, gsum, gcnt, N);
    k_mlp<<<32, 128, 0, stream>>>(gsum, gcnt, p1_w, p1_b, ln_g, ln_b, p2_w, p2_b, out);
}

// Round 15
// 465.318 us; speedup vs baseline: 1.0702x; 1.0010x over previous
//
#include <hip/hip_runtime.h>

#define CDIV(a,b) (((a)+(b)-1)/(b))

typedef __bf16 bf16_t;
typedef unsigned char u8;
typedef bf16_t bf16x8 __attribute__((ext_vector_type(8)));
typedef float floatx4 __attribute__((ext_vector_type(4)));
typedef float floatx2 __attribute__((ext_vector_type(2)));
typedef unsigned uintx4 __attribute__((ext_vector_type(4)));

// sigma2: storage position p -> original feature index (within 256).
__device__ __forceinline__ int sigma2(int p) {
    int tile = p >> 7, hh = (p >> 6) & 1, m = (p >> 2) & 15, c = p & 3;
    return tile * 128 + (hh * 4 + c) * 16 + m;
}

// pack 4 fp32 -> 4 OCP e4m3 bytes
__device__ __forceinline__ unsigned pack4_fp8(float a, float b, float c, float d) {
    int v = __builtin_amdgcn_cvt_pk_fp8_f32(a, b, 0, false);   // bytes [1:0]
    v = __builtin_amdgcn_cvt_pk_fp8_f32(c, d, v, true);        // bytes [3:2]
    return (unsigned)v;
}

template<bool HI>
__device__ __forceinline__ floatx2 cvtf8(unsigned v) {
    return __builtin_amdgcn_cvt_pk_f32_fp8(v, HI);   // HI is constexpr
}

// ---------------------------------------------------------------------------
// K1: per-original-edge degree count (single atomic; edge-attr sum for the
// self-loop fill moved to k_selfloop, which is atomic-free).
__global__ void k_deg(const int* __restrict__ ei, int* __restrict__ deg, int E) {
    int e = blockIdx.x * 256 + threadIdx.x;
    if (e >= E) return;
    atomicAdd(&deg[ei[E + e]], 1);
}

// K3: parallel exclusive scan of (deg[i]+1) -> off[0..n], 3 phases.
__global__ void k_scanA(const int* __restrict__ deg, int* __restrict__ part, int n) {
    __shared__ int sh[256];
    int t = threadIdx.x;
    int i = blockIdx.x * 256 + t;
    int v = (i < n) ? deg[i] + 1 : 0;
    sh[t] = v;
    __syncthreads();
    for (int d = 128; d > 0; d >>= 1) { if (t < d) sh[t] += sh[t + d]; __syncthreads(); }
    if (t == 0) part[blockIdx.x] = sh[0];
}
__global__ void k_scanB(int* __restrict__ part, int nb) {
    __shared__ int sh[256];
    int t = threadIdx.x;
    int v = (t < nb) ? part[t] : 0;
    sh[t] = v;
    __syncthreads();
    for (int d = 1; d < 256; d <<= 1) {
        int u = (t >= d) ? sh[t - d] : 0;
        __syncthreads();
        sh[t] += u;
        __syncthreads();
    }
    if (t < nb) part[t] = sh[t] - v;   // exclusive
}
__global__ void k_scanC(const int* __restrict__ deg, const int* __restrict__ part,
                        int* __restrict__ off, int n) {
    __shared__ int sh[256];
    int t = threadIdx.x;
    int i = blockIdx.x * 256 + t;
    int v = (i < n) ? deg[i] + 1 : 0;
    sh[t] = v;
    __syncthreads();
    for (int d = 1; d < 256; d <<= 1) {
        int u = (t >= d) ? sh[t - d] : 0;
        __syncthreads();
        sh[t] += u;
        __syncthreads();
    }
    int excl = part[blockIdx.x] + sh[t] - v;
    if (i < n) off[i] = excl;
    if (i == n - 1) off[n] = excl + v;
}

// K4: CSR fill of ORIGINAL edges only; originals occupy [off[d], off[d+1]-1),
// the last slot of each segment is reserved for the self-loop (k_selfloop).
__global__ void k_fill(const int* __restrict__ ei, const float* __restrict__ ea,
                       const int* __restrict__ off, int* __restrict__ cursor,
                       int2* __restrict__ csr, int E) {
    int e = blockIdx.x * 256 + threadIdx.x;
    if (e >= E) return;
    int s = ei[e], d = ei[E + e];
    int pos = off[d] + atomicAdd(&cursor[d], 1);
    csr[pos] = make_int2(s, __float_as_int(ea[e]));
}

// K4b: per-node self-loop entry (atomic-free).  Sums the segment's original
// edge attrs -> loop_attr = sum / max(deg,1); writes csr[off[i+1]-1].
__global__ void k_selfloop(const int* __restrict__ off, int2* __restrict__ csr, int n) {
    int i = blockIdx.x * 256 + threadIdx.x;
    if (i >= n) return;
    int p0 = off[i], p1 = off[i + 1] - 1;   // originals in [p0, p1)
    float s = 0.0f;
    for (int p = p0; p < p1; ++p) s += __int_as_float(csr[p].y);
    float la = s / fmaxf((float)(p1 - p0), 1.0f);
    csr[p1] = make_int2(i, __float_as_int(la));
}

// K5c: combined weight transpose+cast Wl,Wr[K,256] fp32 -> Wt[512,K] bf16.
__global__ void k_wcast2(const float* __restrict__ Wl, const float* __restrict__ Wr,
                         const float* __restrict__ bl, const float* __restrict__ br,
                         bf16_t* __restrict__ Wt, float* __restrict__ bias2,
                         int K, int kshift, int permK,
                         const float* __restrict__ we, const float* __restrict__ att,
                         const float* __restrict__ cb,
                         float* __restrict__ wep, float* __restrict__ attp,
                         float* __restrict__ cbp) {
    int idx = blockIdx.x * 256 + threadIdx.x;
    if (idx < 512) bias2[idx] = (idx < 256) ? bl[idx] : br[idx - 256];
    if (idx < 256) {
        int sg = sigma2(idx);
        wep[idx] = we[sg]; attp[idx] = att[sg]; cbp[idx] = cb[sg];
    }
    if (idx >= 512 * K) return;
    int nn = idx >> kshift, k = idx & (K - 1);
    int ks = permK ? sigma2(k) : k;
    float v = (nn < 256) ? Wl[ks * 256 + nn] : Wr[ks * 256 + (nn - 256)];
    Wt[idx] = (bf16_t)v;
}

// K6a: layer-1 GEMM with fused encoder.  grid.y=2 splits the 4 col-tiles.
__global__ __launch_bounds__(256) void k_gemm1_fused(
        const float* __restrict__ x, const float* __restrict__ encw,
        const float* __restrict__ encb, const bf16_t* __restrict__ Wt,
        const float* __restrict__ bias2, u8* __restrict__ XL,
        u8* __restrict__ XR, int nrows) {
    __shared__ bf16_t As[128 * 32];
    __shared__ bf16_t Bs[128 * 32];
    int tid = threadIdx.x;
    int w = tid >> 6, lane = tid & 63;
    int quad = lane >> 4, m = lane & 15;
    int row0 = blockIdx.x * 128;
    int ct0 = blockIdx.y * 2;
    bf16x8 afr[2][2];
    floatx4 acc[2][8];

    for (int ctile = ct0; ctile < ct0 + 2; ++ctile) {
        int n0 = ctile * 128;
#pragma unroll
        for (int rt = 0; rt < 2; ++rt)
#pragma unroll
            for (int ct = 0; ct < 8; ++ct)
                acc[rt][ct] = (floatx4){0.f, 0.f, 0.f, 0.f};
        for (int k0c = 0; k0c < 2; ++k0c) {
            __syncthreads();
            if (ctile == ct0) {
#pragma unroll
                for (int i = 0; i < 2; ++i) {  // stage A: fused encoder
                    int c = tid + i * 256;
                    int r = c >> 2, kc = c & 3;
                    int sw = (kc + (r >> 1)) & 3;
                    int gr = row0 + r; if (gr >= nrows) gr = nrows - 1;
                    float4 xv = ((const float4*)x)[gr];
                    bf16x8 v;
#pragma unroll
                    for (int kk = 0; kk < 8; ++kk) {
                        int k = k0c * 32 + kc * 8 + kk;
                        float s = encb[k];
                        s = fmaf(xv.x, encw[k], s);
                        s = fmaf(xv.y, encw[64 + k], s);
                        s = fmaf(xv.z, encw[128 + k], s);
                        s = fmaf(xv.w, encw[192 + k], s);
                        v[kk] = (bf16_t)fmaxf(s, 0.0f);
                    }
                    *(bf16x8*)&As[r * 32 + sw * 8] = v;
                }
            }
#pragma unroll
            for (int i = 0; i < 2; ++i) {      // stage B for this col-tile
                int c = tid + i * 256;
                int r = c >> 2, kc = c & 3;
                int sw = (kc + (r >> 1)) & 3;
                bf16x8 v = *(const bf16x8*)&Wt[(size_t)(n0 + r) * 64 + k0c * 32 + kc * 8];
                *(bf16x8*)&Bs[r * 32 + sw * 8] = v;
            }
            __syncthreads();
            if (ctile == ct0) {
#pragma unroll
                for (int rt = 0; rt < 2; ++rt) {
                    int ar = w * 32 + rt * 16 + m;
                    afr[k0c][rt] = *(bf16x8*)&As[ar * 32 + (((quad + (ar >> 1)) & 3) * 8)];
                }
            }
            bf16x8 bfr[8];
#pragma unroll
            for (int ct = 0; ct < 8; ++ct) {
                int br = ct * 16 + m;
                bfr[ct] = *(bf16x8*)&Bs[br * 32 + (((quad + (br >> 1)) & 3) * 8)];
            }
#pragma unroll
            for (int ct = 0; ct < 8; ++ct) {
                acc[0][ct] = __builtin_amdgcn_mfma_f32_16x16x32_bf16(afr[k0c][0], bfr[ct], acc[0][ct], 0, 0, 0);
                acc[1][ct] = __builtin_amdgcn_mfma_f32_16x16x32_bf16(afr[k0c][1], bfr[ct], acc[1][ct], 0, 0, 0);
            }
        }
        int tile = ctile & 1;
        u8* dst = (ctile < 2) ? XL : XR;
        float bv[8];
#pragma unroll
        for (int ct = 0; ct < 8; ++ct) bv[ct] = bias2[n0 + ct * 16 + m];
#pragma unroll
        for (int rt = 0; rt < 2; ++rt) {
#pragma unroll
            for (int i = 0; i < 4; ++i) {
                int row = row0 + w * 32 + rt * 16 + quad * 4 + i;
                if (row < nrows) {
                    unsigned w0 = pack4_fp8(acc[rt][0][i] + bv[0], acc[rt][1][i] + bv[1],
                                            acc[rt][2][i] + bv[2], acc[rt][3][i] + bv[3]);
                    unsigned w1 = pack4_fp8(acc[rt][4][i] + bv[4], acc[rt][5][i] + bv[5],
                                            acc[rt][6][i] + bv[6], acc[rt][7][i] + bv[7]);
                    *(unsigned*)&dst[(size_t)row * 256 + tile * 128 + m * 4] = w0;
                    *(unsigned*)&dst[(size_t)row * 256 + tile * 128 + 64 + m * 4] = w1;
                }
            }
        }
    }
}

// K6b: layer-2 GEMM (K=256), grid.y=2 col-tile split; A staged once/block.
__global__ __launch_bounds__(256) void k_gemm2(
        const bf16_t* __restrict__ Hb, const bf16_t* __restrict__ Wt,
        const float* __restrict__ bias2, u8* __restrict__ XL,
        u8* __restrict__ XR, int nrows) {
    const int K = 256;
    __shared__ bf16_t As[128 * 32];
    __shared__ bf16_t Bs[128 * 32];
    int tid = threadIdx.x;
    int w = tid >> 6, lane = tid & 63;
    int quad = lane >> 4, m = lane & 15;
    int row0 = blockIdx.x * 128;
    int ct0 = blockIdx.y * 2;
    bf16x8 afr[8][2];
    floatx4 acc[2][8];

    for (int ctile = ct0; ctile < ct0 + 2; ++ctile) {
        int n0 = ctile * 128;
#pragma unroll
        for (int rt = 0; rt < 2; ++rt)
#pragma unroll
            for (int ct = 0; ct < 8; ++ct)
                acc[rt][ct] = (floatx4){0.f, 0.f, 0.f, 0.f};
        for (int k0c = 0; k0c < 8; ++k0c) {
            __syncthreads();
            if (ctile == ct0) {
#pragma unroll
                for (int i = 0; i < 2; ++i) {
                    int c = tid + i * 256;
                    int r = c >> 2, kc = c & 3;
                    int sw = (kc + (r >> 1)) & 3;
                    int gr = row0 + r; if (gr >= nrows) gr = nrows - 1;
                    bf16x8 v = *(const bf16x8*)&Hb[(size_t)gr * K + k0c * 32 + kc * 8];
                    *(bf16x8*)&As[r * 32 + sw * 8] = v;
                }
            }
#pragma unroll
            for (int i = 0; i < 2; ++i) {
                int c = tid + i * 256;
                int r = c >> 2, kc = c & 3;
                int sw = (kc + (r >> 1)) & 3;
                bf16x8 v = *(const bf16x8*)&Wt[(size_t)(n0 + r) * K + k0c * 32 + kc * 8];
                *(bf16x8*)&Bs[r * 32 + sw * 8] = v;
            }
            __syncthreads();
            if (ctile == ct0) {
#pragma unroll
                for (int rt = 0; rt < 2; ++rt) {
                    int ar = w * 32 + rt * 16 + m;
                    afr[k0c][rt] = *(bf16x8*)&As[ar * 32 + (((quad + (ar >> 1)) & 3) * 8)];
                }
            }
            bf16x8 bfr[8];
#pragma unroll
            for (int ct = 0; ct < 8; ++ct) {
                int br = ct * 16 + m;
                bfr[ct] = *(bf16x8*)&Bs[br * 32 + (((quad + (br >> 1)) & 3) * 8)];
            }
#pragma unroll
            for (int ct = 0; ct < 8; ++ct) {
                acc[0][ct] = __builtin_amdgcn_mfma_f32_16x16x32_bf16(afr[k0c][0], bfr[ct], acc[0][ct], 0, 0, 0);
                acc[1][ct] = __builtin_amdgcn_mfma_f32_16x16x32_bf16(afr[k0c][1], bfr[ct], acc[1][ct], 0, 0, 0);
            }
        }
        int tile = ctile & 1;
        u8* dst = (ctile < 2) ? XL : XR;
        float bv[8];
#pragma unroll
        for (int ct = 0; ct < 8; ++ct) bv[ct] = bias2[n0 + ct * 16 + m];
#pragma unroll
        for (int rt = 0; rt < 2; ++rt) {
#pragma unroll
            for (int i = 0; i < 4; ++i) {
                int row = row0 + w * 32 + rt * 16 + quad * 4 + i;
                if (row < nrows) {
                    unsigned w0 = pack4_fp8(acc[rt][0][i] + bv[0], acc[rt][1][i] + bv[1],
                                            acc[rt][2][i] + bv[2], acc[rt][3][i] + bv[3]);
                    unsigned w1 = pack4_fp8(acc[rt][4][i] + bv[4], acc[rt][5][i] + bv[5],
                                            acc[rt][6][i] + bv[6], acc[rt][7][i] + bv[7]);
                    *(unsigned*)&dst[(size_t)row * 256 + tile * 128 + m * 4] = w0;
                    *(unsigned*)&dst[(size_t)row * 256 + tile * 128 + 64 + m * 4] = w1;
                }
            }
        }
    }
}

// K7: fused GATv2 conv, fp8 XL/XR (256B/edge), sigma2 layout.  One wave per
// dst node, two 32-lane halves on different edges; lane covers 8 features.
// csr loads + Hb stores are NON-TEMPORAL: the 6.8MB edge stream and the
// write-once output otherwise pollute the 4MB per-XCD L2 that the random
// XL gathers need (FETCH already at the XCD-duplication floor ~90MB).
// NOTE: no __launch_bounds__ — R7: higher occupancy thrashes L2.
// NOTE: pool fusion reverted — R9: concurrent same-graph atomics serialize.
__device__ __forceinline__ void pair_step(
        int p, int p1, int half, int loff,
        const int2* __restrict__ csr, const u8* __restrict__ XL,
        floatx2 xr01, floatx2 xr23, floatx2 xr45, floatx2 xr67,
        floatx2 wv01, floatx2 wv23, floatx2 wv45, floatx2 wv67,
        floatx2 av01, floatx2 av23, floatx2 av45, floatx2 av67,
        float& s, floatx2& a01, floatx2& a23, floatx2& a45, floatx2& a67) {
    int idx = p + half;
    bool valid = idx < p1;
    int idc = valid ? idx : p1 - 1;
    long long ev = __builtin_nontemporal_load((const long long*)(csr + idc));
    int src = (int)ev;
    float eav = __int_as_float((int)(ev >> 32));
    uint2 u = *(const uint2*)(XL + (size_t)src * 256 + loff);
    floatx2 x01 = cvtf8<false>(u.x);
    floatx2 x23 = cvtf8<true>(u.x);
    floatx2 x45 = cvtf8<false>(u.y);
    floatx2 x67 = cvtf8<true>(u.y);
    floatx2 t01 = x01 + xr01 + eav * wv01;
    floatx2 t23 = x23 + xr23 + eav * wv23;
    floatx2 t45 = x45 + xr45 + eav * wv45;
    floatx2 t67 = x67 + xr67 + eav * wv67;
    t01 = __builtin_elementwise_max(t01, 0.2f * t01);
    t23 = __builtin_elementwise_max(t23, 0.2f * t23);
    t45 = __builtin_elementwise_max(t45, 0.2f * t45);
    t67 = __builtin_elementwise_max(t67, 0.2f * t67);
    floatx2 d = t01 * av01 + t23 * av23 + t45 * av45 + t67 * av67;
    float al = d.x + d.y;
    al += __shfl_xor(al, 1);
    al += __shfl_xor(al, 2);
    al += __shfl_xor(al, 4);       // 8-lane head group reduce
    float wg = valid ? exp2f(al) : 0.0f;   // att pre-scaled by 1/ln2
    s += wg;
    a01 += wg * x01; a23 += wg * x23; a45 += wg * x45; a67 += wg * x67;
}

__global__ void k_conv(
                       const u8* __restrict__ XL, const u8* __restrict__ XR,
                       const float* __restrict__ wep, const float* __restrict__ attp,
                       const int2* __restrict__ csr,
                       const int* __restrict__ off, const float* __restrict__ cbp,
                       bf16_t* __restrict__ outb, int n) {
    int wid = (blockIdx.x * 256 + threadIdx.x) >> 6;
    int lane = threadIdx.x & 63;
    if (wid >= n) return;
    int l = lane & 31, half = lane >> 5;
    int loff = l * 8;
    uint2 ur = *(const uint2*)(XR + (size_t)wid * 256 + loff);
    floatx2 xr01 = cvtf8<false>(ur.x);
    floatx2 xr23 = cvtf8<true>(ur.x);
    floatx2 xr45 = cvtf8<false>(ur.y);
    floatx2 xr67 = cvtf8<true>(ur.y);
    float4 wa = ((const float4*)wep)[2 * l], wb = ((const float4*)wep)[2 * l + 1];
    float4 aa = ((const float4*)attp)[2 * l], ab = ((const float4*)attp)[2 * l + 1];
    floatx2 wv01 = {wa.x, wa.y}, wv23 = {wa.z, wa.w};
    floatx2 wv45 = {wb.x, wb.y}, wv67 = {wb.z, wb.w};
    const float LOG2E = 1.44269504f;
    floatx2 av01 = {aa.x * LOG2E, aa.y * LOG2E}, av23 = {aa.z * LOG2E, aa.w * LOG2E};
    floatx2 av45 = {ab.x * LOG2E, ab.y * LOG2E}, av67 = {ab.z * LOG2E, ab.w * LOG2E};
    int p0 = off[wid], p1 = off[wid + 1];
    float s = 0.f;
    floatx2 a01 = {0.f, 0.f}, a23 = {0.f, 0.f}, a45 = {0.f, 0.f}, a67 = {0.f, 0.f};
    int p = p0;
    for (; p + 4 <= p1; p += 4) {
        pair_step(p,     p1, half, loff, csr, XL, xr01, xr23, xr45, xr67,
                  wv01, wv23, wv45, wv67, av01, av23, av45, av67, s, a01, a23, a45, a67);
        pair_step(p + 2, p1, half, loff, csr, XL, xr01, xr23, xr45, xr67,
                  wv01, wv23, wv45, wv67, av01, av23, av45, av67, s, a01, a23, a45, a67);
    }
    for (; p < p1; p += 2)
        pair_step(p,     p1, half, loff, csr, XL, xr01, xr23, xr45, xr67,
                  wv01, wv23, wv45, wv67, av01, av23, av45, av67, s, a01, a23, a45, a67);
    // combine the two halves
    s += __shfl_xor(s, 32);
    a01.x += __shfl_xor(a01.x, 32); a01.y += __shfl_xor(a01.y, 32);
    a23.x += __shfl_xor(a23.x, 32); a23.y += __shfl_xor(a23.y, 32);
    a45.x += __shfl_xor(a45.x, 32); a45.y += __shfl_xor(a45.y, 32);
    a67.x += __shfl_xor(a67.x, 32); a67.y += __shfl_xor(a67.y, 32);
    if (half == 0) {
        float inv = 1.0f / s;
        float4 ba = ((const float4*)cbp)[2 * l], bb = ((const float4*)cbp)[2 * l + 1];
        bf16x8 ob;
        ob[0] = (bf16_t)fmaxf(fmaf(a01.x, inv, ba.x), 0.f);
        ob[1] = (bf16_t)fmaxf(fmaf(a01.y, inv, ba.y), 0.f);
        ob[2] = (bf16_t)fmaxf(fmaf(a23.x, inv, ba.z), 0.f);
        ob[3] = (bf16_t)fmaxf(fmaf(a23.y, inv, ba.w), 0.f);
        ob[4] = (bf16_t)fmaxf(fmaf(a45.x, inv, bb.x), 0.f);
        ob[5] = (bf16_t)fmaxf(fmaf(a45.y, inv, bb.y), 0.f);
        ob[6] = (bf16_t)fmaxf(fmaf(a67.x, inv, bb.z), 0.f);
        ob[7] = (bf16_t)fmaxf(fmaf(a67.y, inv, bb.w), 0.f);
        uintx4 obits;
        __builtin_memcpy(&obits, &ob, 16);
        __builtin_nontemporal_store(obits, (uintx4*)&outb[(size_t)wid * 256 + l * 8]);
    }
}

// K9: global mean pool on bf16 input (sigma2 order preserved in gsum).
__global__ void k_pool(const bf16_t* __restrict__ h, const int* __restrict__ batch,
                       float* __restrict__ gsum, float* __restrict__ gcnt, int n) {
    int j = threadIdx.x;
    int start = blockIdx.x * 32;
    if (start >= n) return;
    int end = start + 32; if (end > n) end = n;
    int cur = batch[start];
    float acc = 0.0f, cnt = 0.0f;
    for (int i = start; i < end; ++i) {
        int g = batch[i];
        if (g != cur) {
            atomicAdd(&gsum[cur * 256 + j], acc);
            if (j == 0) atomicAdd(&gcnt[cur], cnt);
            acc = 0.0f; cnt = 0.0f; cur = g;
        }
        acc += (float)h[(size_t)i * 256 + j];
        cnt += 1.0f;
    }
    atomicAdd(&gsum[cur * 256 + j], acc);
    if (j == 0) atomicAdd(&gcnt[cur], cnt);
}

// K10: post MLP.  gsum is in sigma2 order -> un-permute when loading gv.
__global__ void k_mlp(const float* __restrict__ gsum, const float* __restrict__ gcnt,
                      const float* __restrict__ p1w, const float* __restrict__ p1b,
                      const float* __restrict__ lng, const float* __restrict__ lnb,
                      const float* __restrict__ p2w, const float* __restrict__ p2b,
                      float* __restrict__ out) {
    int g = blockIdx.x;
    int t = threadIdx.x; // 128
    __shared__ float gv[256];
    __shared__ float z[128];
    __shared__ float red[128];
    float invc = 1.0f / fmaxf(gcnt[g], 1.0f);
    gv[sigma2(t)]       = gsum[g * 256 + t] * invc;
    gv[sigma2(t + 128)] = gsum[g * 256 + 128 + t] * invc;
    __syncthreads();
    float z1 = p1b[t];
    for (int k = 0; k < 256; ++k) z1 = fmaf(gv[k], p1w[k * 128 + t], z1);
    red[t] = z1;
    __syncthreads();
    for (int d = 64; d > 0; d >>= 1) { if (t < d) red[t] += red[t + d]; __syncthreads(); }
    float mu = red[0] * (1.0f / 128.0f);
    __syncthreads();
    float dz = z1 - mu;
    red[t] = dz * dz;
    __syncthreads();
    for (int d = 64; d > 0; d >>= 1) { if (t < d) red[t] += red[t + d]; __syncthreads(); }
    float var = red[0] * (1.0f / 128.0f);
    float zn = dz * rsqrtf(var + 1e-5f) * lng[t] + lnb[t];
    z[t] = fmaxf(zn, 0.0f);
    __syncthreads();
    if (t < 64) {
        float o = p2b[t];
        for (int k = 0; k < 128; ++k) o = fmaf(z[k], p2w[k * 64 + t], o);
        out[g * 64 + t] = fmaxf(o, 0.0f);
    }
}

extern "C" void kernel_launch(void* const* d_in, const int* in_sizes, int n_in,
                              void* d_out, int out_size, void* d_ws, size_t ws_size,
                              hipStream_t stream) {
    const float* x      = (const float*)d_in[0];
    const int*   ei     = (const int*)d_in[1];
    const float* ea     = (const float*)d_in[2];
    const int*   batch  = (const int*)d_in[3];
    const float* enc_w  = (const float*)d_in[4];
    const float* enc_b  = (const float*)d_in[5];
    const float* g1_wl  = (const float*)d_in[6];
    const float* g1_bl  = (const float*)d_in[7];
    const float* g1_wr  = (const float*)d_in[8];
    const float* g1_br  = (const float*)d_in[9];
    const float* g1_we  = (const float*)d_in[10];
    const float* g1_att = (const float*)d_in[11];
    const float* g1_bias= (const float*)d_in[12];
    const float* g2_wl  = (const float*)d_in[13];
    const float* g2_bl  = (const float*)d_in[14];
    const float* g2_wr  = (const float*)d_in[15];
    const float* g2_br  = (const float*)d_in[16];
    const float* g2_we  = (const float*)d_in[17];
    const float* g2_att = (const float*)d_in[18];
    const float* g2_bias= (const float*)d_in[19];
    const float* p1_w   = (const float*)d_in[20];
    const float* p1_b   = (const float*)d_in[21];
    const float* ln_g   = (const float*)d_in[22];
    const float* ln_b   = (const float*)d_in[23];
    const float* p2_w   = (const float*)d_in[24];
    const float* p2_b   = (const float*)d_in[25];
    float* out = (float*)d_out;

    const int N  = in_sizes[3];
    const int E  = in_sizes[1] / 2;
    const int EE = E + N;
    const int NB = CDIV(N, 256);

    // workspace carve
    u8*     XL  = (u8*)d_ws;                   // [N,256] fp8 (sigma2)
    u8*     XR  = XL + (size_t)N * 256;        // [N,256] fp8 (sigma2)
    bf16_t* Hb  = (bf16_t*)(XR + (size_t)N * 256); // [N,256] bf16 (conv out)
    bf16_t* Wt  = Hb + (size_t)N * 256;        // [512,256] bf16
    int2*  csr  = (int2*)(Wt + 512 * 256);     // [EE] packed {src, ea}
    float* gsum  = (float*)(csr + EE);         // [32*256] -- zeroed region
    float* gcnt  = gsum + 32 * 256;            // [32]
    int*   deg   = (int*)(gcnt + 32);          // [N]
    int*   cursor= deg + N;                    // [N]  -- zeroed region end
    float* bias2 = (float*)(cursor + N);       // [512]
    float* wep   = bias2 + 512;                // [256]
    float* attp  = wep + 256;                  // [256]
    float* cbp   = attp + 256;                 // [256]
    int*   part  = (int*)(cbp + 256);          // [256]
    int*   off   = part + 256;                 // [N+1]

    (void)hipMemsetAsync(gsum, 0, (size_t)(2 * N + 32 * 256 + 32) * sizeof(float), stream);

    k_deg<<<CDIV(E, 256), 256, 0, stream>>>(ei, deg, E);
    k_scanA<<<NB, 256, 0, stream>>>(deg, part, N);
    k_scanB<<<1, 256, 0, stream>>>(part, NB);
    k_scanC<<<NB, 256, 0, stream>>>(deg, part, off, N);
    k_fill<<<CDIV(E, 256), 256, 0, stream>>>(ei, ea, off, cursor, csr, E);
    k_selfloop<<<NB, 256, 0, stream>>>(off, csr, N);

    dim3 ggrid(CDIV(N, 128), 2);

    // ---- GAT layer 1 (encoder fused into GEMM A-staging, K=64) ----
    k_wcast2<<<CDIV(512 * 64, 256), 256, 0, stream>>>(g1_wl, g1_wr, g1_bl, g1_br, Wt, bias2,
                                                      64, 6, 0, g1_we, g1_att, g1_bias,
                                                      wep, attp, cbp);
    k_gemm1_fused<<<ggrid, 256, 0, stream>>>(x, enc_w, enc_b, Wt, bias2, XL, XR, N);
    k_conv<<<CDIV(N, 4), 256, 0, stream>>>(XL, XR, wep, attp, csr, off, cbp, Hb, N);

    // ---- GAT layer 2 (K sigma2-permuted to match Hb layout) ----
    k_wcast2<<<CDIV(512 * 256, 256), 256, 0, stream>>>(g2_wl, g2_wr, g2_bl, g2_br, Wt, bias2,
                                                       256, 8, 1, g2_we, g2_att, g2_bias,
                                                       wep, attp, cbp);
    k_gemm2<<<ggrid, 256, 0, stream>>>(Hb, Wt, bias2, XL, XR, N);
    k_conv<<<CDIV(N, 4), 256, 0, stream>>>(XL, XR, wep, attp, csr, off, cbp, Hb, N);

    // ---- pool + MLP ----
    k_pool<<<CDIV(N, 32), 256, 0, stream>>>(Hb, batch, gsum, gcnt, N);
    k_mlp<<<32, 128, 0, stream>>>(gsum, gcnt, p1_w, p1_b, ln_g, ln_b, p2_w, p2_b, out);
}

// Round 16
// 449.814 us; speedup vs baseline: 1.1071x; 1.0345x over previous
//
#include <hip/hip_runtime.h>

#define CDIV(a,b) (((a)+(b)-1)/(b))

typedef __bf16 bf16_t;
typedef unsigned char u8;
typedef bf16_t bf16x8 __attribute__((ext_vector_type(8)));
typedef float floatx4 __attribute__((ext_vector_type(4)));
typedef float floatx2 __attribute__((ext_vector_type(2)));

// sigma2: storage position p -> original feature index (within 256).
__device__ __forceinline__ int sigma2(int p) {
    int tile = p >> 7, hh = (p >> 6) & 1, m = (p >> 2) & 15, c = p & 3;
    return tile * 128 + (hh * 4 + c) * 16 + m;
}

// pack 4 fp32 -> 4 OCP e4m3 bytes
__device__ __forceinline__ unsigned pack4_fp8(float a, float b, float c, float d) {
    int v = __builtin_amdgcn_cvt_pk_fp8_f32(a, b, 0, false);   // bytes [1:0]
    v = __builtin_amdgcn_cvt_pk_fp8_f32(c, d, v, true);        // bytes [3:2]
    return (unsigned)v;
}

template<bool HI>
__device__ __forceinline__ floatx2 cvtf8(unsigned v) {
    return __builtin_amdgcn_cvt_pk_f32_fp8(v, HI);   // HI is constexpr
}

// ---------------------------------------------------------------------------
// K1: per-original-edge degree count (single atomic; edge-attr sum for the
// self-loop fill moved to k_selfloop, which is atomic-free).
__global__ void k_deg(const int* __restrict__ ei, int* __restrict__ deg, int E) {
    int e = blockIdx.x * 256 + threadIdx.x;
    if (e >= E) return;
    atomicAdd(&deg[ei[E + e]], 1);
}

// K3: parallel exclusive scan of (deg[i]+1) -> off[0..n], 3 phases.
__global__ void k_scanA(const int* __restrict__ deg, int* __restrict__ part, int n) {
    __shared__ int sh[256];
    int t = threadIdx.x;
    int i = blockIdx.x * 256 + t;
    int v = (i < n) ? deg[i] + 1 : 0;
    sh[t] = v;
    __syncthreads();
    for (int d = 128; d > 0; d >>= 1) { if (t < d) sh[t] += sh[t + d]; __syncthreads(); }
    if (t == 0) part[blockIdx.x] = sh[0];
}
__global__ void k_scanB(int* __restrict__ part, int nb) {
    __shared__ int sh[256];
    int t = threadIdx.x;
    int v = (t < nb) ? part[t] : 0;
    sh[t] = v;
    __syncthreads();
    for (int d = 1; d < 256; d <<= 1) {
        int u = (t >= d) ? sh[t - d] : 0;
        __syncthreads();
        sh[t] += u;
        __syncthreads();
    }
    if (t < nb) part[t] = sh[t] - v;   // exclusive
}
__global__ void k_scanC(const int* __restrict__ deg, const int* __restrict__ part,
                        int* __restrict__ off, int n) {
    __shared__ int sh[256];
    int t = threadIdx.x;
    int i = blockIdx.x * 256 + t;
    int v = (i < n) ? deg[i] + 1 : 0;
    sh[t] = v;
    __syncthreads();
    for (int d = 1; d < 256; d <<= 1) {
        int u = (t >= d) ? sh[t - d] : 0;
        __syncthreads();
        sh[t] += u;
        __syncthreads();
    }
    int excl = part[blockIdx.x] + sh[t] - v;
    if (i < n) off[i] = excl;
    if (i == n - 1) off[n] = excl + v;
}

// K4: CSR fill of ORIGINAL edges only; originals occupy [off[d], off[d+1]-1),
// the last slot of each segment is reserved for the self-loop (k_selfloop).
__global__ void k_fill(const int* __restrict__ ei, const float* __restrict__ ea,
                       const int* __restrict__ off, int* __restrict__ cursor,
                       int2* __restrict__ csr, int E) {
    int e = blockIdx.x * 256 + threadIdx.x;
    if (e >= E) return;
    int s = ei[e], d = ei[E + e];
    int pos = off[d] + atomicAdd(&cursor[d], 1);
    csr[pos] = make_int2(s, __float_as_int(ea[e]));
}

// K4b: per-node self-loop entry (atomic-free).  Sums the segment's original
// edge attrs -> loop_attr = sum / max(deg,1); writes csr[off[i+1]-1].
__global__ void k_selfloop(const int* __restrict__ off, int2* __restrict__ csr, int n) {
    int i = blockIdx.x * 256 + threadIdx.x;
    if (i >= n) return;
    int p0 = off[i], p1 = off[i + 1] - 1;   // originals in [p0, p1)
    float s = 0.0f;
    for (int p = p0; p < p1; ++p) s += __int_as_float(csr[p].y);
    float la = s / fmaxf((float)(p1 - p0), 1.0f);
    csr[p1] = make_int2(i, __float_as_int(la));
}

// K5c: combined weight transpose+cast Wl,Wr[K,256] fp32 -> Wt[512,K] bf16.
__global__ void k_wcast2(const float* __restrict__ Wl, const float* __restrict__ Wr,
                         const float* __restrict__ bl, const float* __restrict__ br,
                         bf16_t* __restrict__ Wt, float* __restrict__ bias2,
                         int K, int kshift, int permK,
                         const float* __restrict__ we, const float* __restrict__ att,
                         const float* __restrict__ cb,
                         float* __restrict__ wep, float* __restrict__ attp,
                         float* __restrict__ cbp) {
    int idx = blockIdx.x * 256 + threadIdx.x;
    if (idx < 512) bias2[idx] = (idx < 256) ? bl[idx] : br[idx - 256];
    if (idx < 256) {
        int sg = sigma2(idx);
        wep[idx] = we[sg]; attp[idx] = att[sg]; cbp[idx] = cb[sg];
    }
    if (idx >= 512 * K) return;
    int nn = idx >> kshift, k = idx & (K - 1);
    int ks = permK ? sigma2(k) : k;
    float v = (nn < 256) ? Wl[ks * 256 + nn] : Wr[ks * 256 + (nn - 256)];
    Wt[idx] = (bf16_t)v;
}

// K6a: layer-1 GEMM with fused encoder.  grid.y=2 splits the 4 col-tiles.
__global__ __launch_bounds__(256) void k_gemm1_fused(
        const float* __restrict__ x, const float* __restrict__ encw,
        const float* __restrict__ encb, const bf16_t* __restrict__ Wt,
        const float* __restrict__ bias2, u8* __restrict__ XL,
        u8* __restrict__ XR, int nrows) {
    __shared__ bf16_t As[128 * 32];
    __shared__ bf16_t Bs[128 * 32];
    int tid = threadIdx.x;
    int w = tid >> 6, lane = tid & 63;
    int quad = lane >> 4, m = lane & 15;
    int row0 = blockIdx.x * 128;
    int ct0 = blockIdx.y * 2;
    bf16x8 afr[2][2];
    floatx4 acc[2][8];

    for (int ctile = ct0; ctile < ct0 + 2; ++ctile) {
        int n0 = ctile * 128;
#pragma unroll
        for (int rt = 0; rt < 2; ++rt)
#pragma unroll
            for (int ct = 0; ct < 8; ++ct)
                acc[rt][ct] = (floatx4){0.f, 0.f, 0.f, 0.f};
        for (int k0c = 0; k0c < 2; ++k0c) {
            __syncthreads();
            if (ctile == ct0) {
#pragma unroll
                for (int i = 0; i < 2; ++i) {  // stage A: fused encoder
                    int c = tid + i * 256;
                    int r = c >> 2, kc = c & 3;
                    int sw = (kc + (r >> 1)) & 3;
                    int gr = row0 + r; if (gr >= nrows) gr = nrows - 1;
                    float4 xv = ((const float4*)x)[gr];
                    bf16x8 v;
#pragma unroll
                    for (int kk = 0; kk < 8; ++kk) {
                        int k = k0c * 32 + kc * 8 + kk;
                        float s = encb[k];
                        s = fmaf(xv.x, encw[k], s);
                        s = fmaf(xv.y, encw[64 + k], s);
                        s = fmaf(xv.z, encw[128 + k], s);
                        s = fmaf(xv.w, encw[192 + k], s);
                        v[kk] = (bf16_t)fmaxf(s, 0.0f);
                    }
                    *(bf16x8*)&As[r * 32 + sw * 8] = v;
                }
            }
#pragma unroll
            for (int i = 0; i < 2; ++i) {      // stage B for this col-tile
                int c = tid + i * 256;
                int r = c >> 2, kc = c & 3;
                int sw = (kc + (r >> 1)) & 3;
                bf16x8 v = *(const bf16x8*)&Wt[(size_t)(n0 + r) * 64 + k0c * 32 + kc * 8];
                *(bf16x8*)&Bs[r * 32 + sw * 8] = v;
            }
            __syncthreads();
            if (ctile == ct0) {
#pragma unroll
                for (int rt = 0; rt < 2; ++rt) {
                    int ar = w * 32 + rt * 16 + m;
                    afr[k0c][rt] = *(bf16x8*)&As[ar * 32 + (((quad + (ar >> 1)) & 3) * 8)];
                }
            }
            bf16x8 bfr[8];
#pragma unroll
            for (int ct = 0; ct < 8; ++ct) {
                int br = ct * 16 + m;
                bfr[ct] = *(bf16x8*)&Bs[br * 32 + (((quad + (br >> 1)) & 3) * 8)];
            }
#pragma unroll
            for (int ct = 0; ct < 8; ++ct) {
                acc[0][ct] = __builtin_amdgcn_mfma_f32_16x16x32_bf16(afr[k0c][0], bfr[ct], acc[0][ct], 0, 0, 0);
                acc[1][ct] = __builtin_amdgcn_mfma_f32_16x16x32_bf16(afr[k0c][1], bfr[ct], acc[1][ct], 0, 0, 0);
            }
        }
        int tile = ctile & 1;
        u8* dst = (ctile < 2) ? XL : XR;
        float bv[8];
#pragma unroll
        for (int ct = 0; ct < 8; ++ct) bv[ct] = bias2[n0 + ct * 16 + m];
#pragma unroll
        for (int rt = 0; rt < 2; ++rt) {
#pragma unroll
            for (int i = 0; i < 4; ++i) {
                int row = row0 + w * 32 + rt * 16 + quad * 4 + i;
                if (row < nrows) {
                    unsigned w0 = pack4_fp8(acc[rt][0][i] + bv[0], acc[rt][1][i] + bv[1],
                                            acc[rt][2][i] + bv[2], acc[rt][3][i] + bv[3]);
                    unsigned w1 = pack4_fp8(acc[rt][4][i] + bv[4], acc[rt][5][i] + bv[5],
                                            acc[rt][6][i] + bv[6], acc[rt][7][i] + bv[7]);
                    *(unsigned*)&dst[(size_t)row * 256 + tile * 128 + m * 4] = w0;
                    *(unsigned*)&dst[(size_t)row * 256 + tile * 128 + 64 + m * 4] = w1;
                }
            }
        }
    }
}

// K6b: layer-2 GEMM (K=256), grid.y=2 col-tile split; A staged once/block.
__global__ __launch_bounds__(256) void k_gemm2(
        const bf16_t* __restrict__ Hb, const bf16_t* __restrict__ Wt,
        const float* __restrict__ bias2, u8* __restrict__ XL,
        u8* __restrict__ XR, int nrows) {
    const int K = 256;
    __shared__ bf16_t As[128 * 32];
    __shared__ bf16_t Bs[128 * 32];
    int tid = threadIdx.x;
    int w = tid >> 6, lane = tid & 63;
    int quad = lane >> 4, m = lane & 15;
    int row0 = blockIdx.x * 128;
    int ct0 = blockIdx.y * 2;
    bf16x8 afr[8][2];
    floatx4 acc[2][8];

    for (int ctile = ct0; ctile < ct0 + 2; ++ctile) {
        int n0 = ctile * 128;
#pragma unroll
        for (int rt = 0; rt < 2; ++rt)
#pragma unroll
            for (int ct = 0; ct < 8; ++ct)
                acc[rt][ct] = (floatx4){0.f, 0.f, 0.f, 0.f};
        for (int k0c = 0; k0c < 8; ++k0c) {
            __syncthreads();
            if (ctile == ct0) {
#pragma unroll
                for (int i = 0; i < 2; ++i) {
                    int c = tid + i * 256;
                    int r = c >> 2, kc = c & 3;
                    int sw = (kc + (r >> 1)) & 3;
                    int gr = row0 + r; if (gr >= nrows) gr = nrows - 1;
                    bf16x8 v = *(const bf16x8*)&Hb[(size_t)gr * K + k0c * 32 + kc * 8];
                    *(bf16x8*)&As[r * 32 + sw * 8] = v;
                }
            }
#pragma unroll
            for (int i = 0; i < 2; ++i) {
                int c = tid + i * 256;
                int r = c >> 2, kc = c & 3;
                int sw = (kc + (r >> 1)) & 3;
                bf16x8 v = *(const bf16x8*)&Wt[(size_t)(n0 + r) * K + k0c * 32 + kc * 8];
                *(bf16x8*)&Bs[r * 32 + sw * 8] = v;
            }
            __syncthreads();
            if (ctile == ct0) {
#pragma unroll
                for (int rt = 0; rt < 2; ++rt) {
                    int ar = w * 32 + rt * 16 + m;
                    afr[k0c][rt] = *(bf16x8*)&As[ar * 32 + (((quad + (ar >> 1)) & 3) * 8)];
                }
            }
            bf16x8 bfr[8];
#pragma unroll
            for (int ct = 0; ct < 8; ++ct) {
                int br = ct * 16 + m;
                bfr[ct] = *(bf16x8*)&Bs[br * 32 + (((quad + (br >> 1)) & 3) * 8)];
            }
#pragma unroll
            for (int ct = 0; ct < 8; ++ct) {
                acc[0][ct] = __builtin_amdgcn_mfma_f32_16x16x32_bf16(afr[k0c][0], bfr[ct], acc[0][ct], 0, 0, 0);
                acc[1][ct] = __builtin_amdgcn_mfma_f32_16x16x32_bf16(afr[k0c][1], bfr[ct], acc[1][ct], 0, 0, 0);
            }
        }
        int tile = ctile & 1;
        u8* dst = (ctile < 2) ? XL : XR;
        float bv[8];
#pragma unroll
        for (int ct = 0; ct < 8; ++ct) bv[ct] = bias2[n0 + ct * 16 + m];
#pragma unroll
        for (int rt = 0; rt < 2; ++rt) {
#pragma unroll
            for (int i = 0; i < 4; ++i) {
                int row = row0 + w * 32 + rt * 16 + quad * 4 + i;
                if (row < nrows) {
                    unsigned w0 = pack4_fp8(acc[rt][0][i] + bv[0], acc[rt][1][i] + bv[1],
                                            acc[rt][2][i] + bv[2], acc[rt][3][i] + bv[3]);
                    unsigned w1 = pack4_fp8(acc[rt][4][i] + bv[4], acc[rt][5][i] + bv[5],
                                            acc[rt][6][i] + bv[6], acc[rt][7][i] + bv[7]);
                    *(unsigned*)&dst[(size_t)row * 256 + tile * 128 + m * 4] = w0;
                    *(unsigned*)&dst[(size_t)row * 256 + tile * 128 + 64 + m * 4] = w1;
                }
            }
        }
    }
}

// K7: fused GATv2 conv, fp8 XL/XR (256B/edge), sigma2 layout.  One wave per
// dst node, two 32-lane halves on different edges; lane covers 8 features.
// Plain (cached) csr loads + Hb stores: R15 showed non-temporal hints
// REGRESS conv 83.4->91.4us (FETCH +3.7MB) — the sequential csr stream
// benefits from L2, and NT Hb stores cost gemm2/pool their warm reads.
// NOTE: no __launch_bounds__ — R7: higher occupancy thrashes L2.
// NOTE: pool fusion reverted — R9: concurrent same-graph atomics serialize.
__device__ __forceinline__ void pair_step(
        int p, int p1, int half, int loff,
        const int2* __restrict__ csr, const u8* __restrict__ XL,
        floatx2 xr01, floatx2 xr23, floatx2 xr45, floatx2 xr67,
        floatx2 wv01, floatx2 wv23, floatx2 wv45, floatx2 wv67,
        floatx2 av01, floatx2 av23, floatx2 av45, floatx2 av67,
        float& s, floatx2& a01, floatx2& a23, floatx2& a45, floatx2& a67) {
    int idx = p + half;
    bool valid = idx < p1;
    int idc = valid ? idx : p1 - 1;
    int2 ed = csr[idc];
    int src = ed.x;
    float eav = __int_as_float(ed.y);
    uint2 u = *(const uint2*)(XL + (size_t)src * 256 + loff);
    floatx2 x01 = cvtf8<false>(u.x);
    floatx2 x23 = cvtf8<true>(u.x);
    floatx2 x45 = cvtf8<false>(u.y);
    floatx2 x67 = cvtf8<true>(u.y);
    floatx2 t01 = x01 + xr01 + eav * wv01;
    floatx2 t23 = x23 + xr23 + eav * wv23;
    floatx2 t45 = x45 + xr45 + eav * wv45;
    floatx2 t67 = x67 + xr67 + eav * wv67;
    t01 = __builtin_elementwise_max(t01, 0.2f * t01);
    t23 = __builtin_elementwise_max(t23, 0.2f * t23);
    t45 = __builtin_elementwise_max(t45, 0.2f * t45);
    t67 = __builtin_elementwise_max(t67, 0.2f * t67);
    floatx2 d = t01 * av01 + t23 * av23 + t45 * av45 + t67 * av67;
    float al = d.x + d.y;
    al += __shfl_xor(al, 1);
    al += __shfl_xor(al, 2);
    al += __shfl_xor(al, 4);       // 8-lane head group reduce
    float wg = valid ? exp2f(al) : 0.0f;   // att pre-scaled by 1/ln2
    s += wg;
    a01 += wg * x01; a23 += wg * x23; a45 += wg * x45; a67 += wg * x67;
}

__global__ void k_conv(
                       const u8* __restrict__ XL, const u8* __restrict__ XR,
                       const float* __restrict__ wep, const float* __restrict__ attp,
                       const int2* __restrict__ csr,
                       const int* __restrict__ off, const float* __restrict__ cbp,
                       bf16_t* __restrict__ outb, int n) {
    int wid = (blockIdx.x * 256 + threadIdx.x) >> 6;
    int lane = threadIdx.x & 63;
    if (wid >= n) return;
    int l = lane & 31, half = lane >> 5;
    int loff = l * 8;
    uint2 ur = *(const uint2*)(XR + (size_t)wid * 256 + loff);
    floatx2 xr01 = cvtf8<false>(ur.x);
    floatx2 xr23 = cvtf8<true>(ur.x);
    floatx2 xr45 = cvtf8<false>(ur.y);
    floatx2 xr67 = cvtf8<true>(ur.y);
    float4 wa = ((const float4*)wep)[2 * l], wb = ((const float4*)wep)[2 * l + 1];
    float4 aa = ((const float4*)attp)[2 * l], ab = ((const float4*)attp)[2 * l + 1];
    floatx2 wv01 = {wa.x, wa.y}, wv23 = {wa.z, wa.w};
    floatx2 wv45 = {wb.x, wb.y}, wv67 = {wb.z, wb.w};
    const float LOG2E = 1.44269504f;
    floatx2 av01 = {aa.x * LOG2E, aa.y * LOG2E}, av23 = {aa.z * LOG2E, aa.w * LOG2E};
    floatx2 av45 = {ab.x * LOG2E, ab.y * LOG2E}, av67 = {ab.z * LOG2E, ab.w * LOG2E};
    int p0 = off[wid], p1 = off[wid + 1];
    float s = 0.f;
    floatx2 a01 = {0.f, 0.f}, a23 = {0.f, 0.f}, a45 = {0.f, 0.f}, a67 = {0.f, 0.f};
    int p = p0;
    for (; p + 4 <= p1; p += 4) {
        pair_step(p,     p1, half, loff, csr, XL, xr01, xr23, xr45, xr67,
                  wv01, wv23, wv45, wv67, av01, av23, av45, av67, s, a01, a23, a45, a67);
        pair_step(p + 2, p1, half, loff, csr, XL, xr01, xr23, xr45, xr67,
                  wv01, wv23, wv45, wv67, av01, av23, av45, av67, s, a01, a23, a45, a67);
    }
    for (; p < p1; p += 2)
        pair_step(p,     p1, half, loff, csr, XL, xr01, xr23, xr45, xr67,
                  wv01, wv23, wv45, wv67, av01, av23, av45, av67, s, a01, a23, a45, a67);
    // combine the two halves
    s += __shfl_xor(s, 32);
    a01.x += __shfl_xor(a01.x, 32); a01.y += __shfl_xor(a01.y, 32);
    a23.x += __shfl_xor(a23.x, 32); a23.y += __shfl_xor(a23.y, 32);
    a45.x += __shfl_xor(a45.x, 32); a45.y += __shfl_xor(a45.y, 32);
    a67.x += __shfl_xor(a67.x, 32); a67.y += __shfl_xor(a67.y, 32);
    if (half == 0) {
        float inv = 1.0f / s;
        float4 ba = ((const float4*)cbp)[2 * l], bb = ((const float4*)cbp)[2 * l + 1];
        bf16x8 ob;
        ob[0] = (bf16_t)fmaxf(fmaf(a01.x, inv, ba.x), 0.f);
        ob[1] = (bf16_t)fmaxf(fmaf(a01.y, inv, ba.y), 0.f);
        ob[2] = (bf16_t)fmaxf(fmaf(a23.x, inv, ba.z), 0.f);
        ob[3] = (bf16_t)fmaxf(fmaf(a23.y, inv, ba.w), 0.f);
        ob[4] = (bf16_t)fmaxf(fmaf(a45.x, inv, bb.x), 0.f);
        ob[5] = (bf16_t)fmaxf(fmaf(a45.y, inv, bb.y), 0.f);
        ob[6] = (bf16_t)fmaxf(fmaf(a67.x, inv, bb.z), 0.f);
        ob[7] = (bf16_t)fmaxf(fmaf(a67.y, inv, bb.w), 0.f);
        *(bf16x8*)&outb[(size_t)wid * 256 + l * 8] = ob;
    }
}

// K9: global mean pool on bf16 input (sigma2 order preserved in gsum).
__global__ void k_pool(const bf16_t* __restrict__ h, const int* __restrict__ batch,
                       float* __restrict__ gsum, float* __restrict__ gcnt, int n) {
    int j = threadIdx.x;
    int start = blockIdx.x * 32;
    if (start >= n) return;
    int end = start + 32; if (end > n) end = n;
    int cur = batch[start];
    float acc = 0.0f, cnt = 0.0f;
    for (int i = start; i < end; ++i) {
        int g = batch[i];
        if (g != cur) {
            atomicAdd(&gsum[cur * 256 + j], acc);
            if (j == 0) atomicAdd(&gcnt[cur], cnt);
            acc = 0.0f; cnt = 0.0f; cur = g;
        }
        acc += (float)h[(size_t)i * 256 + j];
        cnt += 1.0f;
    }
    atomicAdd(&gsum[cur * 256 + j], acc);
    if (j == 0) atomicAdd(&gcnt[cur], cnt);
}

// K10: post MLP.  gsum is in sigma2 order -> un-permute when loading gv.
__global__ void k_mlp(const float* __restrict__ gsum, const float* __restrict__ gcnt,
                      const float* __restrict__ p1w, const float* __restrict__ p1b,
                      const float* __restrict__ lng, const float* __restrict__ lnb,
                      const float* __restrict__ p2w, const float* __restrict__ p2b,
                      float* __restrict__ out) {
    int g = blockIdx.x;
    int t = threadIdx.x; // 128
    __shared__ float gv[256];
    __shared__ float z[128];
    __shared__ float red[128];
    float invc = 1.0f / fmaxf(gcnt[g], 1.0f);
    gv[sigma2(t)]       = gsum[g * 256 + t] * invc;
    gv[sigma2(t + 128)] = gsum[g * 256 + 128 + t] * invc;
    __syncthreads();
    float z1 = p1b[t];
    for (int k = 0; k < 256; ++k) z1 = fmaf(gv[k], p1w[k * 128 + t], z1);
    red[t] = z1;
    __syncthreads();
    for (int d = 64; d > 0; d >>= 1) { if (t < d) red[t] += red[t + d]; __syncthreads(); }
    float mu = red[0] * (1.0f / 128.0f);
    __syncthreads();
    float dz = z1 - mu;
    red[t] = dz * dz;
    __syncthreads();
    for (int d = 64; d > 0; d >>= 1) { if (t < d) red[t] += red[t + d]; __syncthreads(); }
    float var = red[0] * (1.0f / 128.0f);
    float zn = dz * rsqrtf(var + 1e-5f) * lng[t] + lnb[t];
    z[t] = fmaxf(zn, 0.0f);
    __syncthreads();
    if (t < 64) {
        float o = p2b[t];
        for (int k = 0; k < 128; ++k) o = fmaf(z[k], p2w[k * 64 + t], o);
        out[g * 64 + t] = fmaxf(o, 0.0f);
    }
}

extern "C" void kernel_launch(void* const* d_in, const int* in_sizes, int n_in,
                              void* d_out, int out_size, void* d_ws, size_t ws_size,
                              hipStream_t stream) {
    const float* x      = (const float*)d_in[0];
    const int*   ei     = (const int*)d_in[1];
    const float* ea     = (const float*)d_in[2];
    const int*   batch  = (const int*)d_in[3];
    const float* enc_w  = (const float*)d_in[4];
    const float* enc_b  = (const float*)d_in[5];
    const float* g1_wl  = (const float*)d_in[6];
    const float* g1_bl  = (const float*)d_in[7];
    const float* g1_wr  = (const float*)d_in[8];
    const float* g1_br  = (const float*)d_in[9];
    const float* g1_we  = (const float*)d_in[10];
    const float* g1_att = (const float*)d_in[11];
    const float* g1_bias= (const float*)d_in[12];
    const float* g2_wl  = (const float*)d_in[13];
    const float* g2_bl  = (const float*)d_in[14];
    const float* g2_wr  = (const float*)d_in[15];
    const float* g2_br  = (const float*)d_in[16];
    const float* g2_we  = (const float*)d_in[17];
    const float* g2_att = (const float*)d_in[18];
    const float* g2_bias= (const float*)d_in[19];
    const float* p1_w   = (const float*)d_in[20];
    const float* p1_b   = (const float*)d_in[21];
    const float* ln_g   = (const float*)d_in[22];
    const float* ln_b   = (const float*)d_in[23];
    const float* p2_w   = (const float*)d_in[24];
    const float* p2_b   = (const float*)d_in[25];
    float* out = (float*)d_out;

    const int N  = in_sizes[3];
    const int E  = in_sizes[1] / 2;
    const int EE = E + N;
    const int NB = CDIV(N, 256);

    // workspace carve
    u8*     XL  = (u8*)d_ws;                   // [N,256] fp8 (sigma2)
    u8*     XR  = XL + (size_t)N * 256;        // [N,256] fp8 (sigma2)
    bf16_t* Hb  = (bf16_t*)(XR + (size_t)N * 256); // [N,256] bf16 (conv out)
    bf16_t* Wt  = Hb + (size_t)N * 256;        // [512,256] bf16
    int2*  csr  = (int2*)(Wt + 512 * 256);     // [EE] packed {src, ea}
    float* gsum  = (float*)(csr + EE);         // [32*256] -- zeroed region
    float* gcnt  = gsum + 32 * 256;            // [32]
    int*   deg   = (int*)(gcnt + 32);          // [N]
    int*   cursor= deg + N;                    // [N]  -- zeroed region end
    float* bias2 = (float*)(cursor + N);       // [512]
    float* wep   = bias2 + 512;                // [256]
    float* attp  = wep + 256;                  // [256]
    float* cbp   = attp + 256;                 // [256]
    int*   part  = (int*)(cbp + 256);          // [256]
    int*   off   = part + 256;                 // [N+1]

    (void)hipMemsetAsync(gsum, 0, (size_t)(2 * N + 32 * 256 + 32) * sizeof(float), stream);

    k_deg<<<CDIV(E, 256), 256, 0, stream>>>(ei, deg, E);
    k_scanA<<<NB, 256, 0, stream>>>(deg, part, N);
    k_scanB<<<1, 256, 0, stream>>>(part, NB);
    k_scanC<<<NB, 256, 0, stream>>>(deg, part, off, N);
    k_fill<<<CDIV(E, 256), 256, 0, stream>>>(ei, ea, off, cursor, csr, E);
    k_selfloop<<<NB, 256, 0, stream>>>(off, csr, N);

    dim3 ggrid(CDIV(N, 128), 2);

    // ---- GAT layer 1 (encoder fused into GEMM A-staging, K=64) ----
    k_wcast2<<<CDIV(512 * 64, 256), 256, 0, stream>>>(g1_wl, g1_wr, g1_bl, g1_br, Wt, bias2,
                                                      64, 6, 0, g1_we, g1_att, g1_bias,
                                                      wep, attp, cbp);
    k_gemm1_fused<<<ggrid, 256, 0, stream>>>(x, enc_w, enc_b, Wt, bias2, XL, XR, N);
    k_conv<<<CDIV(N, 4), 256, 0, stream>>>(XL, XR, wep, attp, csr, off, cbp, Hb, N);

    // ---- GAT layer 2 (K sigma2-permuted to match Hb layout) ----
    k_wcast2<<<CDIV(512 * 256, 256), 256, 0, stream>>>(g2_wl, g2_wr, g2_bl, g2_br, Wt, bias2,
                                                       256, 8, 1, g2_we, g2_att, g2_bias,
                                                       wep, attp, cbp);
    k_gemm2<<<ggrid, 256, 0, stream>>>(Hb, Wt, bias2, XL, XR, N);
    k_conv<<<CDIV(N, 4), 256, 0, stream>>>(XL, XR, wep, attp, csr, off, cbp, Hb, N);

    // ---- pool + MLP ----
    k_pool<<<CDIV(N, 32), 256, 0, stream>>>(Hb, batch, gsum, gcnt, N);
    k_mlp<<<32, 128, 0, stream>>>(gsum, gcnt, p1_w, p1_b, ln_g, ln_b, p2_w, p2_b, out);
}